// Round 1
// baseline (789.771 us; speedup 1.0000x reference)
//
#include <hip/hip_runtime.h>

#define NN 50000
#define EE 800000
#define D 128

static inline size_t align_up(size_t x, size_t a) { return (x + a - 1) & ~(a - 1); }

__global__ void deg_kernel(const int* __restrict__ dst, int* __restrict__ deg, int E) {
    int e = blockIdx.x * blockDim.x + threadIdx.x;
    if (e < E) atomicAdd(&deg[dst[e]], 1);
}

__global__ void dinv_kernel(const int* __restrict__ deg, float* __restrict__ dinv, int n) {
    int i = blockIdx.x * blockDim.x + threadIdx.x;
    if (i < n) {
        float d = (float)deg[i];
        dinv[i] = rsqrtf(d > 1.0f ? d : 1.0f);
    }
}

// Single-block exclusive scan of deg -> rowptr (n+1 entries) and cursor (= rowptr[i])
__global__ void scan_kernel(const int* __restrict__ deg, int* __restrict__ rowptr,
                            int* __restrict__ cursor, int n) {
    __shared__ int wsum[16];
    int tid = threadIdx.x;
    int lane = tid & 63;
    int w = tid >> 6;
    int carry = 0;
    if (tid == 0) rowptr[0] = 0;
    for (int base = 0; base < n; base += 1024) {
        int i = base + tid;
        int v = (i < n) ? deg[i] : 0;
        // wave-inclusive scan
        int sc = v;
        #pragma unroll
        for (int off = 1; off < 64; off <<= 1) {
            int t = __shfl_up(sc, off);
            if (lane >= off) sc += t;
        }
        if (lane == 63) wsum[w] = sc;
        __syncthreads();
        int woff = 0, tot = 0;
        #pragma unroll
        for (int k = 0; k < 16; ++k) {
            int t = wsum[k];
            tot += t;
            if (k < w) woff += t;
        }
        int inc = carry + woff + sc;  // inclusive prefix over whole array
        if (i < n) {
            rowptr[i + 1] = inc;
            cursor[i] = inc - v;      // exclusive
        }
        carry += tot;
        __syncthreads();
    }
}

__global__ void scatter_kernel(const int* __restrict__ src, const int* __restrict__ dst,
                               int* __restrict__ cursor, int* __restrict__ csr_src, int E) {
    int e = blockIdx.x * blockDim.x + threadIdx.x;
    if (e < E) {
        int p = atomicAdd(&cursor[dst[e]], 1);
        csr_src[p] = src[e];
    }
}

// One wave per node. lane owns channels [2*lane, 2*lane+1] as float2.
// MODE 1: out = T1 = -dinv[n] * sum(Xg[s]*dinv[s])            (Xg = feat)
// MODE 2: out = T2 = -2*dinv[n]*sum(...) - feat[n]            (Xg = T1)
// MODE 3: T3 = -2*dinv[n]*sum(...) - T1[n]  (Xg = T2);
//         out = h = th0*feat + 0.5*(th1*T1 + th2*T2 + th3*T3) + 0.5*(th1+th2+th3)
template <int MODE>
__global__ __launch_bounds__(256) void agg_kernel(
    const int* __restrict__ rowptr, const int* __restrict__ csr_src,
    const float* __restrict__ dinv, const float* __restrict__ Xg,
    const float* __restrict__ feat, const float* __restrict__ T1,
    const float* __restrict__ theta, float* __restrict__ outv, int n) {
    int wid = (blockIdx.x * blockDim.x + threadIdx.x) >> 6;
    int lane = threadIdx.x & 63;
    if (wid >= n) return;
    int beg = rowptr[wid];
    int end = rowptr[wid + 1];
    const float2* X2 = (const float2*)Xg;
    float2 acc = make_float2(0.0f, 0.0f);
    for (int e0 = beg; e0 < end; e0 += 64) {
        bool has = (e0 + lane) < end;
        int s = has ? csr_src[e0 + lane] : 0;
        float dsv = has ? dinv[s] : 0.0f;
        int cnt = min(64, end - e0);
        for (int j = 0; j < cnt; ++j) {
            int sj = __shfl(s, j);
            float dj = __shfl(dsv, j);
            float2 v = X2[(size_t)sj * 64 + lane];
            acc.x = fmaf(v.x, dj, acc.x);
            acc.y = fmaf(v.y, dj, acc.y);
        }
    }
    float di = dinv[wid];
    size_t off = (size_t)wid * 64 + lane;
    float2 r;
    if (MODE == 1) {
        r.x = -di * acc.x;
        r.y = -di * acc.y;
    } else if (MODE == 2) {
        float2 f = ((const float2*)feat)[off];
        r.x = -2.0f * di * acc.x - f.x;
        r.y = -2.0f * di * acc.y - f.y;
    } else {
        float2 f = ((const float2*)feat)[off];
        float2 t1 = ((const float2*)T1)[off];
        float2 t2 = ((const float2*)Xg)[off];  // Xg == T2 buffer in mode 3
        float th0 = theta[0], th1 = theta[1], th2 = theta[2], th3 = theta[3];
        float2 t3;
        t3.x = -2.0f * di * acc.x - t1.x;
        t3.y = -2.0f * di * acc.y - t1.y;
        float c = 0.5f * (th1 + th2 + th3);
        r.x = th0 * f.x + 0.5f * (th1 * t1.x + th2 * t2.x + th3 * t3.x) + c;
        r.y = th0 * f.y + 0.5f * (th1 * t1.y + th2 * t2.y + th3 * t3.y) + c;
    }
    ((float2*)outv)[off] = r;
}

// out[n][o] = leaky_relu(sum_i h[n][i] * W[o][i]), W row-major (D_OUT, D_IN)
__global__ __launch_bounds__(256) void gemm_kernel(const float* __restrict__ h,
                                                   const float* __restrict__ W,
                                                   float* __restrict__ out, int n) {
    __shared__ float Ws[D * D];
    int tid = threadIdx.x;
    const float4* W4 = (const float4*)W;
    float4* Ws4 = (float4*)Ws;
    for (int i = tid; i < D * D / 4; i += 256) Ws4[i] = W4[i];
    __syncthreads();
    int node0 = blockIdx.x * 64;
    int o = tid & 127;
    const float4* wr = (const float4*)(Ws + o * D);
    int nend = node0 + 64;
    if (nend > n) nend = n;
    for (int nn = node0 + (tid >> 7); nn < nend; nn += 2) {
        const float4* hr = (const float4*)(h + (size_t)nn * D);
        float acc = 0.0f;
        #pragma unroll 8
        for (int i = 0; i < 32; ++i) {
            float4 a = hr[i];
            float4 b = wr[i];
            acc = fmaf(a.x, b.x, acc);
            acc = fmaf(a.y, b.y, acc);
            acc = fmaf(a.z, b.z, acc);
            acc = fmaf(a.w, b.w, acc);
        }
        float v = acc > 0.0f ? acc : 0.01f * acc;
        out[(size_t)nn * D + o] = v;
    }
}

extern "C" void kernel_launch(void* const* d_in, const int* in_sizes, int n_in,
                              void* d_out, int out_size, void* d_ws, size_t ws_size,
                              hipStream_t stream) {
    const float* feat = (const float*)d_in[0];
    const int* src = (const int*)d_in[1];
    const int* dst = (const int*)d_in[2];
    const float* theta = (const float*)d_in[3];
    const float* W = (const float*)d_in[4];
    float* out = (float*)d_out;

    const int n = NN;
    const int E = EE;

    char* w = (char*)d_ws;
    size_t off = 0;
    int* deg = (int*)(w + off); off = align_up(off + (size_t)n * 4, 512);
    float* dinv = (float*)(w + off); off = align_up(off + (size_t)n * 4, 512);
    int* rowptr = (int*)(w + off); off = align_up(off + (size_t)(n + 1) * 4, 512);
    int* cursor = (int*)(w + off); off = align_up(off + (size_t)n * 4, 512);
    int* csr_src = (int*)(w + off); off = align_up(off + (size_t)E * 4, 512);
    float* T1 = (float*)(w + off); off = align_up(off + (size_t)n * D * 4, 512);
    float* T2 = (float*)(w + off); off = align_up(off + (size_t)n * D * 4, 512);
    (void)ws_size;

    hipMemsetAsync(deg, 0, (size_t)n * 4, stream);

    deg_kernel<<<(E + 255) / 256, 256, 0, stream>>>(dst, deg, E);
    dinv_kernel<<<(n + 255) / 256, 256, 0, stream>>>(deg, dinv, n);
    scan_kernel<<<1, 1024, 0, stream>>>(deg, rowptr, cursor, n);
    scatter_kernel<<<(E + 255) / 256, 256, 0, stream>>>(src, dst, cursor, csr_src, E);

    int agg_grid = (n + 3) / 4;  // 4 waves (nodes) per 256-thread block
    // T1 = L'(feat)
    agg_kernel<1><<<agg_grid, 256, 0, stream>>>(rowptr, csr_src, dinv, feat, feat, T1, theta, T1, n);
    // T2 = 2 L'(T1) - feat
    agg_kernel<2><<<agg_grid, 256, 0, stream>>>(rowptr, csr_src, dinv, T1, feat, T1, theta, T2, n);
    // h (into T1 buffer): uses gathered T2, row-local T1/feat
    agg_kernel<3><<<agg_grid, 256, 0, stream>>>(rowptr, csr_src, dinv, T2, feat, T1, theta, T1, n);

    gemm_kernel<<<(n + 63) / 64, 256, 0, stream>>>(T1, W, out, n);
}

// Round 3
// 372.891 us; speedup vs baseline: 2.1180x; 2.1180x over previous
//
#include <hip/hip_runtime.h>

#define NN 50000
#define EE 800000
#define D 128

static inline size_t align_up(size_t x, size_t a) { return (x + a - 1) & ~(a - 1); }

__global__ void deg_kernel(const int* __restrict__ dst, int* __restrict__ deg, int E) {
    int e = blockIdx.x * blockDim.x + threadIdx.x;
    if (e < E) atomicAdd(&deg[dst[e]], 1);
}

__global__ void dinv_kernel(const int* __restrict__ deg, float* __restrict__ dinv, int n) {
    int i = blockIdx.x * blockDim.x + threadIdx.x;
    if (i < n) {
        float d = (float)deg[i];
        dinv[i] = rsqrtf(d > 1.0f ? d : 1.0f);
    }
}

// Single-block exclusive scan of deg -> rowptr (n+1 entries) and cursor (= rowptr[i])
__global__ void scan_kernel(const int* __restrict__ deg, int* __restrict__ rowptr,
                            int* __restrict__ cursor, int n) {
    __shared__ int wsum[16];
    int tid = threadIdx.x;
    int lane = tid & 63;
    int w = tid >> 6;
    int carry = 0;
    if (tid == 0) rowptr[0] = 0;
    for (int base = 0; base < n; base += 1024) {
        int i = base + tid;
        int v = (i < n) ? deg[i] : 0;
        int sc = v;
        #pragma unroll
        for (int off = 1; off < 64; off <<= 1) {
            int t = __shfl_up(sc, off);
            if (lane >= off) sc += t;
        }
        if (lane == 63) wsum[w] = sc;
        __syncthreads();
        int woff = 0, tot = 0;
        #pragma unroll
        for (int k = 0; k < 16; ++k) {
            int t = wsum[k];
            tot += t;
            if (k < w) woff += t;
        }
        int inc = carry + woff + sc;
        if (i < n) {
            rowptr[i + 1] = inc;
            cursor[i] = inc - v;
        }
        carry += tot;
        __syncthreads();
    }
}

__global__ void scatter_kernel(const int* __restrict__ src, const int* __restrict__ dst,
                               int* __restrict__ cursor, int* __restrict__ csr_src, int E) {
    int e = blockIdx.x * blockDim.x + threadIdx.x;
    if (e < E) {
        int p = atomicAdd(&cursor[dst[e]], 1);
        csr_src[p] = src[e];
    }
}

// One wave per node. lane owns channels [2*lane, 2*lane+1] as float2.
template <int MODE>
__global__ __launch_bounds__(256) void agg_kernel(
    const int* __restrict__ rowptr, const int* __restrict__ csr_src,
    const float* __restrict__ dinv, const float* __restrict__ Xg,
    const float* __restrict__ feat, const float* __restrict__ T1,
    const float* __restrict__ theta, float* __restrict__ outv, int n) {
    int wid = (blockIdx.x * blockDim.x + threadIdx.x) >> 6;
    int lane = threadIdx.x & 63;
    if (wid >= n) return;
    int beg = rowptr[wid];
    int end = rowptr[wid + 1];
    const float2* X2 = (const float2*)Xg;
    float2 acc = make_float2(0.0f, 0.0f);
    for (int e0 = beg; e0 < end; e0 += 64) {
        bool has = (e0 + lane) < end;
        int s = has ? csr_src[e0 + lane] : 0;
        float dsv = has ? dinv[s] : 0.0f;
        int cnt = min(64, end - e0);
        for (int j = 0; j < cnt; ++j) {
            int sj = __shfl(s, j);
            float dj = __shfl(dsv, j);
            float2 v = X2[(size_t)sj * 64 + lane];
            acc.x = fmaf(v.x, dj, acc.x);
            acc.y = fmaf(v.y, dj, acc.y);
        }
    }
    float di = dinv[wid];
    size_t off = (size_t)wid * 64 + lane;
    float2 r;
    if (MODE == 1) {
        r.x = -di * acc.x;
        r.y = -di * acc.y;
    } else if (MODE == 2) {
        float2 f = ((const float2*)feat)[off];
        r.x = -2.0f * di * acc.x - f.x;
        r.y = -2.0f * di * acc.y - f.y;
    } else {
        float2 f = ((const float2*)feat)[off];
        float2 t1 = ((const float2*)T1)[off];
        float2 t2 = ((const float2*)Xg)[off];
        float th0 = theta[0], th1 = theta[1], th2 = theta[2], th3 = theta[3];
        float2 t3;
        t3.x = -2.0f * di * acc.x - t1.x;
        t3.y = -2.0f * di * acc.y - t1.y;
        float c = 0.5f * (th1 + th2 + th3);
        r.x = th0 * f.x + 0.5f * (th1 * t1.x + th2 * t2.x + th3 * t3.x) + c;
        r.y = th0 * f.y + 0.5f * (th1 * t1.y + th2 * t2.y + th3 * t3.y) + c;
    }
    ((float2*)outv)[off] = r;
}

// BK-tiled GEMM: block computes 64 nodes x 64 outs, K in 4 steps of 32.
// LDS tiles stored transposed: hs[kk][r], ws[kk][o], stride 68 floats
// (byte stride 272: 16B-aligned float4 reads; 68 mod 32 = 4 -> conflict-free
// broadcast on h reads, 2-way (free) on W reads).
#define BK 32
#define TS 68
__global__ __launch_bounds__(256) void gemm_kernel(const float* __restrict__ h,
                                                   const float* __restrict__ W,
                                                   float* __restrict__ out, int n) {
    __shared__ float hs[BK * TS];
    __shared__ float ws[BK * TS];
    int tid = threadIdx.x;
    int tile = blockIdx.x >> 1;
    int o0 = (blockIdx.x & 1) * 64;
    int node0 = tile * 64;
    int tx = tid & 15, ty = tid >> 4;  // thread tile: nodes 4*ty.., outs 4*tx..

    float acc[4][4] = {};

    for (int k0 = 0; k0 < D; k0 += BK) {
        __syncthreads();
        #pragma unroll
        for (int p = 0; p < 2; ++p) {
            int idx = p * 256 + tid;
            int r = idx >> 3, c4 = idx & 7;  // row r, float4-col c4
            int nn = node0 + r;
            float4 v = make_float4(0.f, 0.f, 0.f, 0.f);
            if (nn < n) v = ((const float4*)(h + (size_t)nn * D + k0))[c4];
            hs[(c4 * 4 + 0) * TS + r] = v.x;
            hs[(c4 * 4 + 1) * TS + r] = v.y;
            hs[(c4 * 4 + 2) * TS + r] = v.z;
            hs[(c4 * 4 + 3) * TS + r] = v.w;
            float4 wv = ((const float4*)(W + (size_t)(o0 + r) * D + k0))[c4];
            ws[(c4 * 4 + 0) * TS + r] = wv.x;
            ws[(c4 * 4 + 1) * TS + r] = wv.y;
            ws[(c4 * 4 + 2) * TS + r] = wv.z;
            ws[(c4 * 4 + 3) * TS + r] = wv.w;
        }
        __syncthreads();
        #pragma unroll
        for (int kk = 0; kk < BK; ++kk) {
            float4 hv = *(const float4*)&hs[kk * TS + 4 * ty];
            float4 wv = *(const float4*)&ws[kk * TS + 4 * tx];
            float hvv[4] = {hv.x, hv.y, hv.z, hv.w};
            float wvv[4] = {wv.x, wv.y, wv.z, wv.w};
            #pragma unroll
            for (int k = 0; k < 4; ++k)
                #pragma unroll
                for (int kk2 = 0; kk2 < 4; ++kk2)
                    acc[k][kk2] = fmaf(hvv[k], wvv[kk2], acc[k][kk2]);
        }
    }

    #pragma unroll
    for (int k = 0; k < 4; ++k) {
        int nn = node0 + 4 * ty + k;
        if (nn < n) {
            float4 r4;
            r4.x = acc[k][0] > 0.f ? acc[k][0] : 0.01f * acc[k][0];
            r4.y = acc[k][1] > 0.f ? acc[k][1] : 0.01f * acc[k][1];
            r4.z = acc[k][2] > 0.f ? acc[k][2] : 0.01f * acc[k][2];
            r4.w = acc[k][3] > 0.f ? acc[k][3] : 0.01f * acc[k][3];
            ((float4*)(out + (size_t)nn * D + o0))[tx] = r4;
        }
    }
}

extern "C" void kernel_launch(void* const* d_in, const int* in_sizes, int n_in,
                              void* d_out, int out_size, void* d_ws, size_t ws_size,
                              hipStream_t stream) {
    const float* feat = (const float*)d_in[0];
    const int* src = (const int*)d_in[1];
    const int* dst = (const int*)d_in[2];
    const float* theta = (const float*)d_in[3];
    const float* W = (const float*)d_in[4];
    float* out = (float*)d_out;

    const int n = NN;
    const int E = EE;

    char* w = (char*)d_ws;
    size_t off = 0;
    int* deg = (int*)(w + off); off = align_up(off + (size_t)n * 4, 512);
    float* dinv = (float*)(w + off); off = align_up(off + (size_t)n * 4, 512);
    int* rowptr = (int*)(w + off); off = align_up(off + (size_t)(n + 1) * 4, 512);
    int* cursor = (int*)(w + off); off = align_up(off + (size_t)n * 4, 512);
    int* csr_src = (int*)(w + off); off = align_up(off + (size_t)E * 4, 512);
    float* T1 = (float*)(w + off); off = align_up(off + (size_t)n * D * 4, 512);
    float* T2 = (float*)(w + off); off = align_up(off + (size_t)n * D * 4, 512);
    (void)ws_size;

    hipMemsetAsync(deg, 0, (size_t)n * 4, stream);

    deg_kernel<<<(E + 255) / 256, 256, 0, stream>>>(dst, deg, E);
    dinv_kernel<<<(n + 255) / 256, 256, 0, stream>>>(deg, dinv, n);
    scan_kernel<<<1, 1024, 0, stream>>>(deg, rowptr, cursor, n);
    scatter_kernel<<<(E + 255) / 256, 256, 0, stream>>>(src, dst, cursor, csr_src, E);

    int agg_grid = (n + 3) / 4;
    agg_kernel<1><<<agg_grid, 256, 0, stream>>>(rowptr, csr_src, dinv, feat, feat, T1, theta, T1, n);
    agg_kernel<2><<<agg_grid, 256, 0, stream>>>(rowptr, csr_src, dinv, T1, feat, T1, theta, T2, n);
    agg_kernel<3><<<agg_grid, 256, 0, stream>>>(rowptr, csr_src, dinv, T2, feat, T1, theta, T1, n);

    int gemm_grid = ((n + 63) / 64) * 2;
    gemm_kernel<<<gemm_grid, 256, 0, stream>>>(T1, W, out, n);
}

// Round 5
// 307.299 us; speedup vs baseline: 2.5700x; 1.2134x over previous
//
#include <hip/hip_runtime.h>

#define NN 50000
#define EE 800000
#define D 128

static inline size_t align_up(size_t x, size_t a) { return (x + a - 1) & ~(a - 1); }

__device__ __forceinline__ unsigned pack_bf16(float a, float b) {
    unsigned ua = __float_as_uint(a), ub = __float_as_uint(b);
    unsigned ra = (ua + 0x7fffu + ((ua >> 16) & 1u)) >> 16;
    unsigned rb = (ub + 0x7fffu + ((ub >> 16) & 1u)) & 0xffff0000u;
    return ra | rb;
}

__global__ void deg_kernel(const int* __restrict__ dst, int* __restrict__ deg, int E) {
    int e = blockIdx.x * blockDim.x + threadIdx.x;
    if (e < E) atomicAdd(&deg[dst[e]], 1);
}

__global__ void dinv_kernel(const int* __restrict__ deg, float* __restrict__ dinv, int n) {
    int i = blockIdx.x * blockDim.x + threadIdx.x;
    if (i < n) {
        float d = (float)deg[i];
        dinv[i] = rsqrtf(d > 1.0f ? d : 1.0f);
    }
}

// featb[i][c2] = bf16x2(feat[i][2c2]*dinv[i], feat[i][2c2+1]*dinv[i])
__global__ void scale_kernel(const float* __restrict__ feat, const float* __restrict__ dinv,
                             unsigned* __restrict__ featb, int n) {
    int idx = blockIdx.x * blockDim.x + threadIdx.x;
    if (idx >= n * 64) return;
    int i = idx >> 6;
    float di = dinv[i];
    float2 f = ((const float2*)feat)[idx];
    featb[idx] = pack_bf16(f.x * di, f.y * di);
}

// Hierarchical scan: per-block inclusive scan (256 elems/block) + block totals
__global__ void scan_blk_kernel(const int* __restrict__ deg, int* __restrict__ bscan,
                                int* __restrict__ btot, int n) {
    __shared__ int ws4[4];
    int tid = threadIdx.x, b = blockIdx.x;
    int i = b * 256 + tid;
    int v = (i < n) ? deg[i] : 0;
    int lane = tid & 63, w = tid >> 6;
    int sc = v;
    #pragma unroll
    for (int off = 1; off < 64; off <<= 1) {
        int t = __shfl_up(sc, off);
        if (lane >= off) sc += t;
    }
    if (lane == 63) ws4[w] = sc;
    __syncthreads();
    int woff = 0;
    #pragma unroll
    for (int k = 0; k < 4; ++k)
        if (k < w) woff += ws4[k];
    int inc = sc + woff;
    bscan[b * 256 + tid] = inc;
    if (tid == 255) btot[b] = inc;
}

// Single block: exclusive scan of nb block totals in place
__global__ void scan_top_kernel(int* __restrict__ btot, int nb) {
    __shared__ int ws4[4];
    int tid = threadIdx.x;
    int v = (tid < nb) ? btot[tid] : 0;
    int lane = tid & 63, w = tid >> 6;
    int sc = v;
    #pragma unroll
    for (int off = 1; off < 64; off <<= 1) {
        int t = __shfl_up(sc, off);
        if (lane >= off) sc += t;
    }
    if (lane == 63) ws4[w] = sc;
    __syncthreads();
    int woff = 0;
    #pragma unroll
    for (int k = 0; k < 4; ++k)
        if (k < w) woff += ws4[k];
    if (tid < nb) btot[tid] = sc + woff - v;  // exclusive
}

__global__ void scan_fix_kernel(const int* __restrict__ bscan, const int* __restrict__ btot,
                                const int* __restrict__ deg, int* __restrict__ rowptr,
                                int* __restrict__ cursor, int n) {
    int i = blockIdx.x * blockDim.x + threadIdx.x;
    if (i >= n) return;
    int inc = bscan[i] + btot[i >> 8];
    rowptr[i + 1] = inc;
    cursor[i] = inc - deg[i];
    if (i == 0) rowptr[0] = 0;
}

__global__ void scatter_kernel(const int* __restrict__ src, const int* __restrict__ dst,
                               int* __restrict__ cursor, int* __restrict__ csr_src, int E) {
    int e = blockIdx.x * blockDim.x + threadIdx.x;
    if (e < E) {
        int p = atomicAdd(&cursor[dst[e]], 1);
        csr_src[p] = src[e];
    }
}

// One wave per node; lane owns channels [2*lane, 2*lane+1].
// Gathers pre-scaled bf16 rows Xb (acc = sum over src of bf16(T*dinv)[s]).
template <int MODE>
__global__ __launch_bounds__(256) void agg_kernel(
    const int* __restrict__ rowptr, const int* __restrict__ csr_src,
    const float* __restrict__ dinv, const unsigned* __restrict__ Xb,
    const float* __restrict__ feat, const float* __restrict__ T1f,
    const float* __restrict__ T2f, const float* __restrict__ theta,
    float* __restrict__ outf, unsigned* __restrict__ outb, int n) {
    int wid = (blockIdx.x * blockDim.x + threadIdx.x) >> 6;
    int lane = threadIdx.x & 63;
    if (wid >= n) return;
    int beg = rowptr[wid];
    int end = rowptr[wid + 1];
    float ax = 0.0f, ay = 0.0f;
    for (int e0 = beg; e0 < end; e0 += 64) {
        int s = (e0 + lane < end) ? csr_src[e0 + lane] : 0;
        int cnt = min(64, end - e0);
        for (int j = 0; j < cnt; ++j) {
            int sj = __shfl(s, j);
            unsigned u = Xb[(size_t)sj * 64 + lane];
            ax += __uint_as_float(u << 16);
            ay += __uint_as_float(u & 0xffff0000u);
        }
    }
    float di = dinv[wid];
    size_t off = (size_t)wid * 64 + lane;
    if (MODE == 1) {
        float rx = -di * ax, ry = -di * ay;
        ((float2*)outf)[off] = make_float2(rx, ry);
        outb[off] = pack_bf16(rx * di, ry * di);
    } else if (MODE == 2) {
        float2 f = ((const float2*)feat)[off];
        float rx = -2.0f * di * ax - f.x;
        float ry = -2.0f * di * ay - f.y;
        ((float2*)outf)[off] = make_float2(rx, ry);
        outb[off] = pack_bf16(rx * di, ry * di);
    } else {
        float2 f = ((const float2*)feat)[off];
        float2 t1 = ((const float2*)T1f)[off];
        float2 t2 = ((const float2*)T2f)[off];
        float th0 = theta[0], th1 = theta[1], th2 = theta[2], th3 = theta[3];
        float t3x = -2.0f * di * ax - t1.x;
        float t3y = -2.0f * di * ay - t1.y;
        float c = 0.5f * (th1 + th2 + th3);
        float rx = th0 * f.x + 0.5f * (th1 * t1.x + th2 * t2.x + th3 * t3x) + c;
        float ry = th0 * f.y + 0.5f * (th1 * t1.y + th2 * t2.y + th3 * t3y) + c;
        ((float2*)outf)[off] = make_float2(rx, ry);
    }
}

// BK-tiled GEMM: block computes 64 nodes x 64 outs, K in 4 steps of 32.
#define BK 32
#define TS 68
__global__ __launch_bounds__(256) void gemm_kernel(const float* __restrict__ h,
                                                   const float* __restrict__ W,
                                                   float* __restrict__ out, int n) {
    __shared__ float hs[BK * TS];
    __shared__ float ws[BK * TS];
    int tid = threadIdx.x;
    int tile = blockIdx.x >> 1;
    int o0 = (blockIdx.x & 1) * 64;
    int node0 = tile * 64;
    int tx = tid & 15, ty = tid >> 4;

    float acc[4][4] = {};

    for (int k0 = 0; k0 < D; k0 += BK) {
        __syncthreads();
        #pragma unroll
        for (int p = 0; p < 2; ++p) {
            int idx = p * 256 + tid;
            int r = idx >> 3, c4 = idx & 7;
            int nn = node0 + r;
            float4 v = make_float4(0.f, 0.f, 0.f, 0.f);
            if (nn < n) v = ((const float4*)(h + (size_t)nn * D + k0))[c4];
            hs[(c4 * 4 + 0) * TS + r] = v.x;
            hs[(c4 * 4 + 1) * TS + r] = v.y;
            hs[(c4 * 4 + 2) * TS + r] = v.z;
            hs[(c4 * 4 + 3) * TS + r] = v.w;
            float4 wv = ((const float4*)(W + (size_t)(o0 + r) * D + k0))[c4];
            ws[(c4 * 4 + 0) * TS + r] = wv.x;
            ws[(c4 * 4 + 1) * TS + r] = wv.y;
            ws[(c4 * 4 + 2) * TS + r] = wv.z;
            ws[(c4 * 4 + 3) * TS + r] = wv.w;
        }
        __syncthreads();
        #pragma unroll
        for (int kk = 0; kk < BK; ++kk) {
            float4 hv = *(const float4*)&hs[kk * TS + 4 * ty];
            float4 wv = *(const float4*)&ws[kk * TS + 4 * tx];
            float hvv[4] = {hv.x, hv.y, hv.z, hv.w};
            float wvv[4] = {wv.x, wv.y, wv.z, wv.w};
            #pragma unroll
            for (int k = 0; k < 4; ++k)
                #pragma unroll
                for (int kk2 = 0; kk2 < 4; ++kk2)
                    acc[k][kk2] = fmaf(hvv[k], wvv[kk2], acc[k][kk2]);
        }
    }

    #pragma unroll
    for (int k = 0; k < 4; ++k) {
        int nn = node0 + 4 * ty + k;
        if (nn < n) {
            float4 r4;
            r4.x = acc[k][0] > 0.f ? acc[k][0] : 0.01f * acc[k][0];
            r4.y = acc[k][1] > 0.f ? acc[k][1] : 0.01f * acc[k][1];
            r4.z = acc[k][2] > 0.f ? acc[k][2] : 0.01f * acc[k][2];
            r4.w = acc[k][3] > 0.f ? acc[k][3] : 0.01f * acc[k][3];
            ((float4*)(out + (size_t)nn * D + o0))[tx] = r4;
        }
    }
}

extern "C" void kernel_launch(void* const* d_in, const int* in_sizes, int n_in,
                              void* d_out, int out_size, void* d_ws, size_t ws_size,
                              hipStream_t stream) {
    const float* feat = (const float*)d_in[0];
    const int* src = (const int*)d_in[1];
    const int* dst = (const int*)d_in[2];
    const float* theta = (const float*)d_in[3];
    const float* W = (const float*)d_in[4];
    float* out = (float*)d_out;

    const int n = NN;
    const int E = EE;
    const int nb = (n + 255) / 256;

    char* w = (char*)d_ws;
    size_t off = 0;
    int* deg = (int*)(w + off); off = align_up(off + (size_t)n * 4, 512);
    float* dinv = (float*)(w + off); off = align_up(off + (size_t)n * 4, 512);
    int* rowptr = (int*)(w + off); off = align_up(off + (size_t)(n + 1) * 4, 512);
    int* cursor = (int*)(w + off); off = align_up(off + (size_t)n * 4, 512);
    int* bscan = (int*)(w + off); off = align_up(off + (size_t)(nb * 256) * 4, 512);
    int* btot = (int*)(w + off); off = align_up(off + (size_t)256 * 4, 512);
    int* csr_src = (int*)(w + off); off = align_up(off + (size_t)E * 4, 512);
    unsigned* featb = (unsigned*)(w + off); off = align_up(off + (size_t)n * 64 * 4, 512);
    float* T1f = (float*)(w + off); off = align_up(off + (size_t)n * D * 4, 512);
    unsigned* T1b = (unsigned*)(w + off); off = align_up(off + (size_t)n * 64 * 4, 512);
    float* T2f = (float*)(w + off); off = align_up(off + (size_t)n * D * 4, 512);
    unsigned* T2b = (unsigned*)(w + off); off = align_up(off + (size_t)n * 64 * 4, 512);
    (void)ws_size;

    hipMemsetAsync(deg, 0, (size_t)n * 4, stream);

    deg_kernel<<<(E + 255) / 256, 256, 0, stream>>>(dst, deg, E);
    dinv_kernel<<<(n + 255) / 256, 256, 0, stream>>>(deg, dinv, n);
    scale_kernel<<<(n * 64 + 255) / 256, 256, 0, stream>>>(feat, dinv, featb, n);
    scan_blk_kernel<<<nb, 256, 0, stream>>>(deg, bscan, btot, n);
    scan_top_kernel<<<1, 256, 0, stream>>>(btot, nb);
    scan_fix_kernel<<<(n + 255) / 256, 256, 0, stream>>>(bscan, btot, deg, rowptr, cursor, n);
    scatter_kernel<<<(E + 255) / 256, 256, 0, stream>>>(src, dst, cursor, csr_src, E);

    int agg_grid = (n + 3) / 4;
    agg_kernel<1><<<agg_grid, 256, 0, stream>>>(rowptr, csr_src, dinv, featb, feat, T1f, T2f, theta, T1f, T1b, n);
    agg_kernel<2><<<agg_grid, 256, 0, stream>>>(rowptr, csr_src, dinv, T1b, feat, T1f, T2f, theta, T2f, T2b, n);
    agg_kernel<3><<<agg_grid, 256, 0, stream>>>(rowptr, csr_src, dinv, T2b, feat, T1f, T2f, theta, T1f, (unsigned*)0, n);

    int gemm_grid = ((n + 63) / 64) * 2;
    gemm_kernel<<<gemm_grid, 256, 0, stream>>>(T1f, W, out, n);
}

// Round 6
// 250.634 us; speedup vs baseline: 3.1511x; 1.2261x over previous
//
#include <hip/hip_runtime.h>

#define NN 50000
#define EE 800000
#define D 128

static inline size_t align_up(size_t x, size_t a) { return (x + a - 1) & ~(a - 1); }

__device__ __forceinline__ unsigned pack_bf16(float a, float b) {
    unsigned ua = __float_as_uint(a), ub = __float_as_uint(b);
    unsigned ra = (ua + 0x7fffu + ((ua >> 16) & 1u)) >> 16;
    unsigned rb = (ub + 0x7fffu + ((ub >> 16) & 1u)) & 0xffff0000u;
    return ra | rb;
}
__device__ __forceinline__ float bf_lo(unsigned u) { return __uint_as_float(u << 16); }
__device__ __forceinline__ float bf_hi(unsigned u) { return __uint_as_float(u & 0xffff0000u); }

__global__ void deg_kernel(const int* __restrict__ dst, int* __restrict__ deg, int E) {
    int e = blockIdx.x * blockDim.x + threadIdx.x;
    if (e < E) atomicAdd(&deg[dst[e]], 1);
}

__global__ void dinv_kernel(const int* __restrict__ deg, float* __restrict__ dinv, int n) {
    int i = blockIdx.x * blockDim.x + threadIdx.x;
    if (i < n) {
        float d = (float)deg[i];
        dinv[i] = rsqrtf(d > 1.0f ? d : 1.0f);
    }
}

__global__ void scale_kernel(const float* __restrict__ feat, const float* __restrict__ dinv,
                             unsigned* __restrict__ featb, int n) {
    int idx = blockIdx.x * blockDim.x + threadIdx.x;
    if (idx >= n * 64) return;
    int i = idx >> 6;
    float di = dinv[i];
    float2 f = ((const float2*)feat)[idx];
    featb[idx] = pack_bf16(f.x * di, f.y * di);
}

__global__ void scan_blk_kernel(const int* __restrict__ deg, int* __restrict__ bscan,
                                int* __restrict__ btot, int n) {
    __shared__ int ws4[4];
    int tid = threadIdx.x, b = blockIdx.x;
    int i = b * 256 + tid;
    int v = (i < n) ? deg[i] : 0;
    int lane = tid & 63, w = tid >> 6;
    int sc = v;
    #pragma unroll
    for (int off = 1; off < 64; off <<= 1) {
        int t = __shfl_up(sc, off);
        if (lane >= off) sc += t;
    }
    if (lane == 63) ws4[w] = sc;
    __syncthreads();
    int woff = 0;
    #pragma unroll
    for (int k = 0; k < 4; ++k)
        if (k < w) woff += ws4[k];
    int inc = sc + woff;
    bscan[b * 256 + tid] = inc;
    if (tid == 255) btot[b] = inc;
}

__global__ void scan_top_kernel(int* __restrict__ btot, int nb) {
    __shared__ int ws4[4];
    int tid = threadIdx.x;
    int v = (tid < nb) ? btot[tid] : 0;
    int lane = tid & 63, w = tid >> 6;
    int sc = v;
    #pragma unroll
    for (int off = 1; off < 64; off <<= 1) {
        int t = __shfl_up(sc, off);
        if (lane >= off) sc += t;
    }
    if (lane == 63) ws4[w] = sc;
    __syncthreads();
    int woff = 0;
    #pragma unroll
    for (int k = 0; k < 4; ++k)
        if (k < w) woff += ws4[k];
    if (tid < nb) btot[tid] = sc + woff - v;
}

__global__ void scan_fix_kernel(const int* __restrict__ bscan, const int* __restrict__ btot,
                                const int* __restrict__ deg, int* __restrict__ rowptr,
                                int* __restrict__ cursor, int n) {
    int i = blockIdx.x * blockDim.x + threadIdx.x;
    if (i >= n) return;
    int inc = bscan[i] + btot[i >> 8];
    rowptr[i + 1] = inc;
    cursor[i] = inc - deg[i];
    if (i == 0) rowptr[0] = 0;
}

__global__ void scatter_kernel(const int* __restrict__ src, const int* __restrict__ dst,
                               int* __restrict__ cursor, int* __restrict__ csr_src, int E) {
    int e = blockIdx.x * blockDim.x + threadIdx.x;
    if (e < E) {
        int p = atomicAdd(&cursor[dst[e]], 1);
        csr_src[p] = src[e];
    }
}

// One wave per node. Half-wave edge pairing: lanes 0-31 = edge j, lanes 32-63 = edge j+1.
// Lane (l&31)=hl owns channels [4hl..4hl+3], loading uint2 (4 bf16) per edge.
// Xb rows are pre-scaled by dinv[src]; acc folded across halves at the end.
template <int MODE>
__global__ __launch_bounds__(256) void agg_kernel(
    const int* __restrict__ rowptr, const int* __restrict__ csr_src,
    const float* __restrict__ dinv, const unsigned* __restrict__ Xb,
    const float* __restrict__ feat, const float* __restrict__ T1f,
    const float* __restrict__ T2f, const float* __restrict__ theta,
    float* __restrict__ outf, unsigned* __restrict__ outb, int n) {
    int wid = (blockIdx.x * blockDim.x + threadIdx.x) >> 6;
    int lane = threadIdx.x & 63;
    if (wid >= n) return;
    int half = lane >> 5;
    int hl = lane & 31;
    int beg = rowptr[wid];
    int end = rowptr[wid + 1];
    const uint2* X2 = (const uint2*)Xb;
    float a0 = 0.f, a1 = 0.f, a2 = 0.f, a3 = 0.f;
    for (int e0 = beg; e0 < end; e0 += 64) {
        int s = (e0 + lane < end) ? csr_src[e0 + lane] : 0;
        int cnt = min(64, end - e0);
        int j = 0;
        // 4-pair (8-edge) batches: 4 independent gathers in flight
        for (; j + 8 <= cnt; j += 8) {
            int s0 = __shfl(s, j + 0 + half);
            int s1 = __shfl(s, j + 2 + half);
            int s2 = __shfl(s, j + 4 + half);
            int s3 = __shfl(s, j + 6 + half);
            uint2 u0 = X2[(size_t)s0 * 32 + hl];
            uint2 u1 = X2[(size_t)s1 * 32 + hl];
            uint2 u2 = X2[(size_t)s2 * 32 + hl];
            uint2 u3 = X2[(size_t)s3 * 32 + hl];
            a0 += bf_lo(u0.x); a1 += bf_hi(u0.x); a2 += bf_lo(u0.y); a3 += bf_hi(u0.y);
            a0 += bf_lo(u1.x); a1 += bf_hi(u1.x); a2 += bf_lo(u1.y); a3 += bf_hi(u1.y);
            a0 += bf_lo(u2.x); a1 += bf_hi(u2.x); a2 += bf_lo(u2.y); a3 += bf_hi(u2.y);
            a0 += bf_lo(u3.x); a1 += bf_hi(u3.x); a2 += bf_lo(u3.y); a3 += bf_hi(u3.y);
        }
        for (; j + 2 <= cnt; j += 2) {
            int sj = __shfl(s, j + half);
            uint2 u = X2[(size_t)sj * 32 + hl];
            a0 += bf_lo(u.x); a1 += bf_hi(u.x); a2 += bf_lo(u.y); a3 += bf_hi(u.y);
        }
        if (j < cnt) {  // odd remainder: half 0 only
            int sj = __shfl(s, j);
            if (half == 0) {
                uint2 u = X2[(size_t)sj * 32 + hl];
                a0 += bf_lo(u.x); a1 += bf_hi(u.x); a2 += bf_lo(u.y); a3 += bf_hi(u.y);
            }
        }
    }
    // fold the two halves
    a0 += __shfl_xor(a0, 32);
    a1 += __shfl_xor(a1, 32);
    a2 += __shfl_xor(a2, 32);
    a3 += __shfl_xor(a3, 32);

    float di = dinv[wid];
    size_t row4 = (size_t)wid * 32 + hl;
    float r0, r1, r2, r3;
    if (MODE == 1) {
        r0 = -di * a0; r1 = -di * a1; r2 = -di * a2; r3 = -di * a3;
    } else if (MODE == 2) {
        float4 f = ((const float4*)feat)[row4];
        r0 = -2.f * di * a0 - f.x;
        r1 = -2.f * di * a1 - f.y;
        r2 = -2.f * di * a2 - f.z;
        r3 = -2.f * di * a3 - f.w;
    } else {
        float4 f = ((const float4*)feat)[row4];
        float4 t1 = ((const float4*)T1f)[row4];
        float4 t2 = ((const float4*)T2f)[row4];
        float th0 = theta[0], th1 = theta[1], th2 = theta[2], th3 = theta[3];
        float c = 0.5f * (th1 + th2 + th3);
        float t30 = -2.f * di * a0 - t1.x;
        float t31 = -2.f * di * a1 - t1.y;
        float t32 = -2.f * di * a2 - t1.z;
        float t33 = -2.f * di * a3 - t1.w;
        r0 = th0 * f.x + 0.5f * (th1 * t1.x + th2 * t2.x + th3 * t30) + c;
        r1 = th0 * f.y + 0.5f * (th1 * t1.y + th2 * t2.y + th3 * t31) + c;
        r2 = th0 * f.z + 0.5f * (th1 * t1.z + th2 * t2.z + th3 * t32) + c;
        r3 = th0 * f.w + 0.5f * (th1 * t1.w + th2 * t2.w + th3 * t33) + c;
    }
    if (half == 0) {
        ((float4*)outf)[row4] = make_float4(r0, r1, r2, r3);
    } else if (MODE != 3) {
        uint2 p;
        p.x = pack_bf16(r0 * di, r1 * di);
        p.y = pack_bf16(r2 * di, r3 * di);
        ((uint2*)outb)[row4] = p;
    }
}

// BK-tiled GEMM: block computes 64 nodes x 64 outs, K in 4 steps of 32.
#define BK 32
#define TS 68
__global__ __launch_bounds__(256) void gemm_kernel(const float* __restrict__ h,
                                                   const float* __restrict__ W,
                                                   float* __restrict__ out, int n) {
    __shared__ float hs[BK * TS];
    __shared__ float ws[BK * TS];
    int tid = threadIdx.x;
    int tile = blockIdx.x >> 1;
    int o0 = (blockIdx.x & 1) * 64;
    int node0 = tile * 64;
    int tx = tid & 15, ty = tid >> 4;

    float acc[4][4] = {};

    for (int k0 = 0; k0 < D; k0 += BK) {
        __syncthreads();
        #pragma unroll
        for (int p = 0; p < 2; ++p) {
            int idx = p * 256 + tid;
            int r = idx >> 3, c4 = idx & 7;
            int nn = node0 + r;
            float4 v = make_float4(0.f, 0.f, 0.f, 0.f);
            if (nn < n) v = ((const float4*)(h + (size_t)nn * D + k0))[c4];
            hs[(c4 * 4 + 0) * TS + r] = v.x;
            hs[(c4 * 4 + 1) * TS + r] = v.y;
            hs[(c4 * 4 + 2) * TS + r] = v.z;
            hs[(c4 * 4 + 3) * TS + r] = v.w;
            float4 wv = ((const float4*)(W + (size_t)(o0 + r) * D + k0))[c4];
            ws[(c4 * 4 + 0) * TS + r] = wv.x;
            ws[(c4 * 4 + 1) * TS + r] = wv.y;
            ws[(c4 * 4 + 2) * TS + r] = wv.z;
            ws[(c4 * 4 + 3) * TS + r] = wv.w;
        }
        __syncthreads();
        #pragma unroll
        for (int kk = 0; kk < BK; ++kk) {
            float4 hv = *(const float4*)&hs[kk * TS + 4 * ty];
            float4 wv = *(const float4*)&ws[kk * TS + 4 * tx];
            float hvv[4] = {hv.x, hv.y, hv.z, hv.w};
            float wvv[4] = {wv.x, wv.y, wv.z, wv.w};
            #pragma unroll
            for (int k = 0; k < 4; ++k)
                #pragma unroll
                for (int kk2 = 0; kk2 < 4; ++kk2)
                    acc[k][kk2] = fmaf(hvv[k], wvv[kk2], acc[k][kk2]);
        }
    }

    #pragma unroll
    for (int k = 0; k < 4; ++k) {
        int nn = node0 + 4 * ty + k;
        if (nn < n) {
            float4 r4;
            r4.x = acc[k][0] > 0.f ? acc[k][0] : 0.01f * acc[k][0];
            r4.y = acc[k][1] > 0.f ? acc[k][1] : 0.01f * acc[k][1];
            r4.z = acc[k][2] > 0.f ? acc[k][2] : 0.01f * acc[k][2];
            r4.w = acc[k][3] > 0.f ? acc[k][3] : 0.01f * acc[k][3];
            ((float4*)(out + (size_t)nn * D + o0))[tx] = r4;
        }
    }
}

extern "C" void kernel_launch(void* const* d_in, const int* in_sizes, int n_in,
                              void* d_out, int out_size, void* d_ws, size_t ws_size,
                              hipStream_t stream) {
    const float* feat = (const float*)d_in[0];
    const int* src = (const int*)d_in[1];
    const int* dst = (const int*)d_in[2];
    const float* theta = (const float*)d_in[3];
    const float* W = (const float*)d_in[4];
    float* out = (float*)d_out;

    const int n = NN;
    const int E = EE;
    const int nb = (n + 255) / 256;

    char* w = (char*)d_ws;
    size_t off = 0;
    int* deg = (int*)(w + off); off = align_up(off + (size_t)n * 4, 512);
    float* dinv = (float*)(w + off); off = align_up(off + (size_t)n * 4, 512);
    int* rowptr = (int*)(w + off); off = align_up(off + (size_t)(n + 1) * 4, 512);
    int* cursor = (int*)(w + off); off = align_up(off + (size_t)n * 4, 512);
    int* bscan = (int*)(w + off); off = align_up(off + (size_t)(nb * 256) * 4, 512);
    int* btot = (int*)(w + off); off = align_up(off + (size_t)256 * 4, 512);
    int* csr_src = (int*)(w + off); off = align_up(off + (size_t)E * 4, 512);
    unsigned* featb = (unsigned*)(w + off); off = align_up(off + (size_t)n * 64 * 4, 512);
    float* T1f = (float*)(w + off); off = align_up(off + (size_t)n * D * 4, 512);
    unsigned* T1b = (unsigned*)(w + off); off = align_up(off + (size_t)n * 64 * 4, 512);
    float* T2f = (float*)(w + off); off = align_up(off + (size_t)n * D * 4, 512);
    unsigned* T2b = (unsigned*)(w + off); off = align_up(off + (size_t)n * 64 * 4, 512);
    (void)ws_size;

    hipMemsetAsync(deg, 0, (size_t)n * 4, stream);

    deg_kernel<<<(E + 255) / 256, 256, 0, stream>>>(dst, deg, E);
    dinv_kernel<<<(n + 255) / 256, 256, 0, stream>>>(deg, dinv, n);
    scale_kernel<<<(n * 64 + 255) / 256, 256, 0, stream>>>(feat, dinv, featb, n);
    scan_blk_kernel<<<nb, 256, 0, stream>>>(deg, bscan, btot, n);
    scan_top_kernel<<<1, 256, 0, stream>>>(btot, nb);
    scan_fix_kernel<<<(n + 255) / 256, 256, 0, stream>>>(bscan, btot, deg, rowptr, cursor, n);
    scatter_kernel<<<(E + 255) / 256, 256, 0, stream>>>(src, dst, cursor, csr_src, E);

    int agg_grid = (n + 3) / 4;
    agg_kernel<1><<<agg_grid, 256, 0, stream>>>(rowptr, csr_src, dinv, featb, feat, T1f, T2f, theta, T1f, T1b, n);
    agg_kernel<2><<<agg_grid, 256, 0, stream>>>(rowptr, csr_src, dinv, T1b, feat, T1f, T2f, theta, T2f, T2b, n);
    agg_kernel<3><<<agg_grid, 256, 0, stream>>>(rowptr, csr_src, dinv, T2b, feat, T1f, T2f, theta, T1f, (unsigned*)0, n);

    int gemm_grid = ((n + 63) / 64) * 2;
    gemm_kernel<<<gemm_grid, 256, 0, stream>>>(T1f, W, out, n);
}

// Round 7
// 238.523 us; speedup vs baseline: 3.3111x; 1.0508x over previous
//
#include <hip/hip_runtime.h>

#define NN 50000
#define EE 800000
#define D 128
#define PARTSZ 6250  // NN/8

static inline size_t align_up(size_t x, size_t a) { return (x + a - 1) & ~(a - 1); }

__device__ __forceinline__ unsigned pack_bf16(float a, float b) {
    unsigned ua = __float_as_uint(a), ub = __float_as_uint(b);
    unsigned ra = (ua + 0x7fffu + ((ua >> 16) & 1u)) >> 16;
    unsigned rb = (ub + 0x7fffu + ((ub >> 16) & 1u)) & 0xffff0000u;
    return ra | rb;
}
__device__ __forceinline__ float bf_lo(unsigned u) { return __uint_as_float(u << 16); }
__device__ __forceinline__ float bf_hi(unsigned u) { return __uint_as_float(u & 0xffff0000u); }

// dst-partitioned degree histogram: block b covers chunk b>>3, partition b&7.
// Atomics for any given deg line come from blocks of one partition only.
__global__ __launch_bounds__(256) void deg_kernel(const int* __restrict__ dst,
                                                  int* __restrict__ deg, int E) {
    int part = blockIdx.x & 7;
    int nch = gridDim.x >> 3;
    int chunk = blockIdx.x >> 3;
    int per = (E + nch - 1) / nch;
    int beg = chunk * per;
    int end = min(E, beg + per);
    int plo = part * PARTSZ, phi = plo + PARTSZ;
    for (int e = beg + threadIdx.x; e < end; e += 256) {
        int d = dst[e];
        if (d >= plo && d < phi) atomicAdd(&deg[d], 1);
    }
}

__global__ void dinv_kernel(const int* __restrict__ deg, float* __restrict__ dinv, int n) {
    int i = blockIdx.x * blockDim.x + threadIdx.x;
    if (i < n) {
        float d = (float)deg[i];
        dinv[i] = rsqrtf(d > 1.0f ? d : 1.0f);
    }
}

__global__ void scale_kernel(const float* __restrict__ feat, const float* __restrict__ dinv,
                             unsigned* __restrict__ featb, int n) {
    int idx = blockIdx.x * blockDim.x + threadIdx.x;
    if (idx >= n * 64) return;
    int i = idx >> 6;
    float di = dinv[i];
    float2 f = ((const float2*)feat)[idx];
    featb[idx] = pack_bf16(f.x * di, f.y * di);
}

__global__ void scan_blk_kernel(const int* __restrict__ deg, int* __restrict__ bscan,
                                int* __restrict__ btot, int n) {
    __shared__ int ws4[4];
    int tid = threadIdx.x, b = blockIdx.x;
    int i = b * 256 + tid;
    int v = (i < n) ? deg[i] : 0;
    int lane = tid & 63, w = tid >> 6;
    int sc = v;
    #pragma unroll
    for (int off = 1; off < 64; off <<= 1) {
        int t = __shfl_up(sc, off);
        if (lane >= off) sc += t;
    }
    if (lane == 63) ws4[w] = sc;
    __syncthreads();
    int woff = 0;
    #pragma unroll
    for (int k = 0; k < 4; ++k)
        if (k < w) woff += ws4[k];
    int inc = sc + woff;
    bscan[b * 256 + tid] = inc;
    if (tid == 255) btot[b] = inc;
}

__global__ void scan_top_kernel(int* __restrict__ btot, int nb) {
    __shared__ int ws4[4];
    int tid = threadIdx.x;
    int v = (tid < nb) ? btot[tid] : 0;
    int lane = tid & 63, w = tid >> 6;
    int sc = v;
    #pragma unroll
    for (int off = 1; off < 64; off <<= 1) {
        int t = __shfl_up(sc, off);
        if (lane >= off) sc += t;
    }
    if (lane == 63) ws4[w] = sc;
    __syncthreads();
    int woff = 0;
    #pragma unroll
    for (int k = 0; k < 4; ++k)
        if (k < w) woff += ws4[k];
    if (tid < nb) btot[tid] = sc + woff - v;
}

__global__ void scan_fix_kernel(const int* __restrict__ bscan, const int* __restrict__ btot,
                                const int* __restrict__ deg, int* __restrict__ rowptr,
                                int* __restrict__ cursor, int n) {
    int i = blockIdx.x * blockDim.x + threadIdx.x;
    if (i >= n) return;
    int inc = bscan[i] + btot[i >> 8];
    rowptr[i + 1] = inc;
    cursor[i] = inc - deg[i];
    if (i == 0) rowptr[0] = 0;
}

// dst-partitioned counting-sort scatter: same chunk/partition scheme as deg_kernel.
// Writes to any csr_src line come from one partition -> one XCD's L2.
__global__ __launch_bounds__(256) void scatter_kernel(const int* __restrict__ src,
                                                      const int* __restrict__ dst,
                                                      int* __restrict__ cursor,
                                                      int* __restrict__ csr_src, int E) {
    int part = blockIdx.x & 7;
    int nch = gridDim.x >> 3;
    int chunk = blockIdx.x >> 3;
    int per = (E + nch - 1) / nch;
    int beg = chunk * per;
    int end = min(E, beg + per);
    int plo = part * PARTSZ, phi = plo + PARTSZ;
    for (int e = beg + threadIdx.x; e < end; e += 256) {
        int d = dst[e];
        int s = src[e];
        if (d >= plo && d < phi) {
            int p = atomicAdd(&cursor[d], 1);
            csr_src[p] = s;
        }
    }
}

// One wave per node. Half-wave edge pairing: lanes 0-31 = edge j, lanes 32-63 = edge j+1.
// Lane (l&31)=hl owns channels [4hl..4hl+3], loading uint2 (4 bf16) per edge.
template <int MODE>
__global__ __launch_bounds__(256) void agg_kernel(
    const int* __restrict__ rowptr, const int* __restrict__ csr_src,
    const float* __restrict__ dinv, const unsigned* __restrict__ Xb,
    const float* __restrict__ feat, const float* __restrict__ T1f,
    const float* __restrict__ T2f, const float* __restrict__ theta,
    float* __restrict__ outf, unsigned* __restrict__ outb, int n) {
    int wid = (blockIdx.x * blockDim.x + threadIdx.x) >> 6;
    int lane = threadIdx.x & 63;
    if (wid >= n) return;
    int half = lane >> 5;
    int hl = lane & 31;
    int beg = rowptr[wid];
    int end = rowptr[wid + 1];
    const uint2* X2 = (const uint2*)Xb;
    float a0 = 0.f, a1 = 0.f, a2 = 0.f, a3 = 0.f;
    for (int e0 = beg; e0 < end; e0 += 64) {
        int s = (e0 + lane < end) ? csr_src[e0 + lane] : 0;
        int cnt = min(64, end - e0);
        int j = 0;
        for (; j + 8 <= cnt; j += 8) {
            int s0 = __shfl(s, j + 0 + half);
            int s1 = __shfl(s, j + 2 + half);
            int s2 = __shfl(s, j + 4 + half);
            int s3 = __shfl(s, j + 6 + half);
            uint2 u0 = X2[(size_t)s0 * 32 + hl];
            uint2 u1 = X2[(size_t)s1 * 32 + hl];
            uint2 u2 = X2[(size_t)s2 * 32 + hl];
            uint2 u3 = X2[(size_t)s3 * 32 + hl];
            a0 += bf_lo(u0.x); a1 += bf_hi(u0.x); a2 += bf_lo(u0.y); a3 += bf_hi(u0.y);
            a0 += bf_lo(u1.x); a1 += bf_hi(u1.x); a2 += bf_lo(u1.y); a3 += bf_hi(u1.y);
            a0 += bf_lo(u2.x); a1 += bf_hi(u2.x); a2 += bf_lo(u2.y); a3 += bf_hi(u2.y);
            a0 += bf_lo(u3.x); a1 += bf_hi(u3.x); a2 += bf_lo(u3.y); a3 += bf_hi(u3.y);
        }
        for (; j + 2 <= cnt; j += 2) {
            int sj = __shfl(s, j + half);
            uint2 u = X2[(size_t)sj * 32 + hl];
            a0 += bf_lo(u.x); a1 += bf_hi(u.x); a2 += bf_lo(u.y); a3 += bf_hi(u.y);
        }
        if (j < cnt) {
            int sj = __shfl(s, j);
            if (half == 0) {
                uint2 u = X2[(size_t)sj * 32 + hl];
                a0 += bf_lo(u.x); a1 += bf_hi(u.x); a2 += bf_lo(u.y); a3 += bf_hi(u.y);
            }
        }
    }
    a0 += __shfl_xor(a0, 32);
    a1 += __shfl_xor(a1, 32);
    a2 += __shfl_xor(a2, 32);
    a3 += __shfl_xor(a3, 32);

    float di = dinv[wid];
    size_t row4 = (size_t)wid * 32 + hl;
    float r0, r1, r2, r3;
    if (MODE == 1) {
        r0 = -di * a0; r1 = -di * a1; r2 = -di * a2; r3 = -di * a3;
    } else if (MODE == 2) {
        float4 f = ((const float4*)feat)[row4];
        r0 = -2.f * di * a0 - f.x;
        r1 = -2.f * di * a1 - f.y;
        r2 = -2.f * di * a2 - f.z;
        r3 = -2.f * di * a3 - f.w;
    } else {
        float4 f = ((const float4*)feat)[row4];
        float4 t1 = ((const float4*)T1f)[row4];
        float4 t2 = ((const float4*)T2f)[row4];
        float th0 = theta[0], th1 = theta[1], th2 = theta[2], th3 = theta[3];
        float c = 0.5f * (th1 + th2 + th3);
        float t30 = -2.f * di * a0 - t1.x;
        float t31 = -2.f * di * a1 - t1.y;
        float t32 = -2.f * di * a2 - t1.z;
        float t33 = -2.f * di * a3 - t1.w;
        r0 = th0 * f.x + 0.5f * (th1 * t1.x + th2 * t2.x + th3 * t30) + c;
        r1 = th0 * f.y + 0.5f * (th1 * t1.y + th2 * t2.y + th3 * t31) + c;
        r2 = th0 * f.z + 0.5f * (th1 * t1.z + th2 * t2.z + th3 * t32) + c;
        r3 = th0 * f.w + 0.5f * (th1 * t1.w + th2 * t2.w + th3 * t33) + c;
    }
    if (half == 0) {
        ((float4*)outf)[row4] = make_float4(r0, r1, r2, r3);
    } else if (MODE != 3) {
        uint2 p;
        p.x = pack_bf16(r0 * di, r1 * di);
        p.y = pack_bf16(r2 * di, r3 * di);
        ((uint2*)outb)[row4] = p;
    }
}

// BK-tiled GEMM: block computes 64 nodes x 64 outs, K in 4 steps of 32.
#define BK 32
#define TS 68
__global__ __launch_bounds__(256) void gemm_kernel(const float* __restrict__ h,
                                                   const float* __restrict__ W,
                                                   float* __restrict__ out, int n) {
    __shared__ float hs[BK * TS];
    __shared__ float ws[BK * TS];
    int tid = threadIdx.x;
    int tile = blockIdx.x >> 1;
    int o0 = (blockIdx.x & 1) * 64;
    int node0 = tile * 64;
    int tx = tid & 15, ty = tid >> 4;

    float acc[4][4] = {};

    for (int k0 = 0; k0 < D; k0 += BK) {
        __syncthreads();
        #pragma unroll
        for (int p = 0; p < 2; ++p) {
            int idx = p * 256 + tid;
            int r = idx >> 3, c4 = idx & 7;
            int nn = node0 + r;
            float4 v = make_float4(0.f, 0.f, 0.f, 0.f);
            if (nn < n) v = ((const float4*)(h + (size_t)nn * D + k0))[c4];
            hs[(c4 * 4 + 0) * TS + r] = v.x;
            hs[(c4 * 4 + 1) * TS + r] = v.y;
            hs[(c4 * 4 + 2) * TS + r] = v.z;
            hs[(c4 * 4 + 3) * TS + r] = v.w;
            float4 wv = ((const float4*)(W + (size_t)(o0 + r) * D + k0))[c4];
            ws[(c4 * 4 + 0) * TS + r] = wv.x;
            ws[(c4 * 4 + 1) * TS + r] = wv.y;
            ws[(c4 * 4 + 2) * TS + r] = wv.z;
            ws[(c4 * 4 + 3) * TS + r] = wv.w;
        }
        __syncthreads();
        #pragma unroll
        for (int kk = 0; kk < BK; ++kk) {
            float4 hv = *(const float4*)&hs[kk * TS + 4 * ty];
            float4 wv = *(const float4*)&ws[kk * TS + 4 * tx];
            float hvv[4] = {hv.x, hv.y, hv.z, hv.w};
            float wvv[4] = {wv.x, wv.y, wv.z, wv.w};
            #pragma unroll
            for (int k = 0; k < 4; ++k)
                #pragma unroll
                for (int kk2 = 0; kk2 < 4; ++kk2)
                    acc[k][kk2] = fmaf(hvv[k], wvv[kk2], acc[k][kk2]);
        }
    }

    #pragma unroll
    for (int k = 0; k < 4; ++k) {
        int nn = node0 + 4 * ty + k;
        if (nn < n) {
            float4 r4;
            r4.x = acc[k][0] > 0.f ? acc[k][0] : 0.01f * acc[k][0];
            r4.y = acc[k][1] > 0.f ? acc[k][1] : 0.01f * acc[k][1];
            r4.z = acc[k][2] > 0.f ? acc[k][2] : 0.01f * acc[k][2];
            r4.w = acc[k][3] > 0.f ? acc[k][3] : 0.01f * acc[k][3];
            ((float4*)(out + (size_t)nn * D + o0))[tx] = r4;
        }
    }
}

extern "C" void kernel_launch(void* const* d_in, const int* in_sizes, int n_in,
                              void* d_out, int out_size, void* d_ws, size_t ws_size,
                              hipStream_t stream) {
    const float* feat = (const float*)d_in[0];
    const int* src = (const int*)d_in[1];
    const int* dst = (const int*)d_in[2];
    const float* theta = (const float*)d_in[3];
    const float* W = (const float*)d_in[4];
    float* out = (float*)d_out;

    const int n = NN;
    const int E = EE;
    const int nb = (n + 255) / 256;

    char* w = (char*)d_ws;
    size_t off = 0;
    int* deg = (int*)(w + off); off = align_up(off + (size_t)n * 4, 512);
    float* dinv = (float*)(w + off); off = align_up(off + (size_t)n * 4, 512);
    int* rowptr = (int*)(w + off); off = align_up(off + (size_t)(n + 1) * 4, 512);
    int* cursor = (int*)(w + off); off = align_up(off + (size_t)n * 4, 512);
    int* bscan = (int*)(w + off); off = align_up(off + (size_t)(nb * 256) * 4, 512);
    int* btot = (int*)(w + off); off = align_up(off + (size_t)256 * 4, 512);
    int* csr_src = (int*)(w + off); off = align_up(off + (size_t)E * 4, 512);
    unsigned* featb = (unsigned*)(w + off); off = align_up(off + (size_t)n * 64 * 4, 512);
    float* T1f = (float*)(w + off); off = align_up(off + (size_t)n * D * 4, 512);
    unsigned* T1b = (unsigned*)(w + off); off = align_up(off + (size_t)n * 64 * 4, 512);
    float* T2f = (float*)(w + off); off = align_up(off + (size_t)n * D * 4, 512);
    unsigned* T2b = (unsigned*)(w + off); off = align_up(off + (size_t)n * 64 * 4, 512);
    (void)ws_size;

    hipMemsetAsync(deg, 0, (size_t)n * 4, stream);

    deg_kernel<<<2048, 256, 0, stream>>>(dst, deg, E);
    dinv_kernel<<<(n + 255) / 256, 256, 0, stream>>>(deg, dinv, n);
    scale_kernel<<<(n * 64 + 255) / 256, 256, 0, stream>>>(feat, dinv, featb, n);
    scan_blk_kernel<<<nb, 256, 0, stream>>>(deg, bscan, btot, n);
    scan_top_kernel<<<1, 256, 0, stream>>>(btot, nb);
    scan_fix_kernel<<<(n + 255) / 256, 256, 0, stream>>>(bscan, btot, deg, rowptr, cursor, n);
    scatter_kernel<<<2048, 256, 0, stream>>>(src, dst, cursor, csr_src, E);

    int agg_grid = (n + 3) / 4;
    agg_kernel<1><<<agg_grid, 256, 0, stream>>>(rowptr, csr_src, dinv, featb, feat, T1f, T2f, theta, T1f, T1b, n);
    agg_kernel<2><<<agg_grid, 256, 0, stream>>>(rowptr, csr_src, dinv, T1b, feat, T1f, T2f, theta, T2f, T2b, n);
    agg_kernel<3><<<agg_grid, 256, 0, stream>>>(rowptr, csr_src, dinv, T2b, feat, T1f, T2f, theta, T1f, (unsigned*)0, n);

    int gemm_grid = ((n + 63) / 64) * 2;
    gemm_kernel<<<gemm_grid, 256, 0, stream>>>(T1f, W, out, n);
}

// Round 8
// 227.663 us; speedup vs baseline: 3.4690x; 1.0477x over previous
//
#include <hip/hip_runtime.h>

#define NN 50000
#define EE 800000
#define D 128
#define PARTSZ 6250  // NN/8

static inline size_t align_up(size_t x, size_t a) { return (x + a - 1) & ~(a - 1); }

__device__ __forceinline__ unsigned pack_bf16(float a, float b) {
    unsigned ua = __float_as_uint(a), ub = __float_as_uint(b);
    unsigned ra = (ua + 0x7fffu + ((ua >> 16) & 1u)) >> 16;
    unsigned rb = (ub + 0x7fffu + ((ub >> 16) & 1u)) & 0xffff0000u;
    return ra | rb;
}
__device__ __forceinline__ float bf_lo(unsigned u) { return __uint_as_float(u << 16); }
__device__ __forceinline__ float bf_hi(unsigned u) { return __uint_as_float(u & 0xffff0000u); }

__global__ void zero_kernel(int* __restrict__ p, int n) {
    int i = blockIdx.x * blockDim.x + threadIdx.x;
    if (i < n) p[i] = 0;
}

// dst-partitioned degree histogram: block b covers chunk b>>3, partition b&7.
__global__ __launch_bounds__(256) void deg_kernel(const int* __restrict__ dst,
                                                  int* __restrict__ deg, int E) {
    int part = blockIdx.x & 7;
    int nch = gridDim.x >> 3;
    int chunk = blockIdx.x >> 3;
    int per = (E + nch - 1) / nch;
    int beg = chunk * per;
    int end = min(E, beg + per);
    int plo = part * PARTSZ, phi = plo + PARTSZ;
    for (int e = beg + threadIdx.x; e < end; e += 256) {
        int d = dst[e];
        if (d >= plo && d < phi) atomicAdd(&deg[d], 1);
    }
}

__global__ void dinv_kernel(const int* __restrict__ deg, float* __restrict__ dinv,
                            float* __restrict__ rdinv, int n) {
    int i = blockIdx.x * blockDim.x + threadIdx.x;
    if (i < n) {
        float d = (float)deg[i];
        if (d < 1.0f) d = 1.0f;
        dinv[i] = rsqrtf(d);
        rdinv[i] = sqrtf(d);
    }
}

__global__ void scale_kernel(const float* __restrict__ feat, const float* __restrict__ dinv,
                             unsigned* __restrict__ featb, int n) {
    int idx = blockIdx.x * blockDim.x + threadIdx.x;
    if (idx >= n * 64) return;
    int i = idx >> 6;
    float di = dinv[i];
    float2 f = ((const float2*)feat)[idx];
    featb[idx] = pack_bf16(f.x * di, f.y * di);
}

__global__ void scan_blk_kernel(const int* __restrict__ deg, int* __restrict__ bscan,
                                int* __restrict__ btot, int n) {
    __shared__ int ws4[4];
    int tid = threadIdx.x, b = blockIdx.x;
    int i = b * 256 + tid;
    int v = (i < n) ? deg[i] : 0;
    int lane = tid & 63, w = tid >> 6;
    int sc = v;
    #pragma unroll
    for (int off = 1; off < 64; off <<= 1) {
        int t = __shfl_up(sc, off);
        if (lane >= off) sc += t;
    }
    if (lane == 63) ws4[w] = sc;
    __syncthreads();
    int woff = 0;
    #pragma unroll
    for (int k = 0; k < 4; ++k)
        if (k < w) woff += ws4[k];
    int inc = sc + woff;
    bscan[b * 256 + tid] = inc;
    if (tid == 255) btot[b] = inc;
}

__global__ void scan_top_kernel(int* __restrict__ btot, int nb) {
    __shared__ int ws4[4];
    int tid = threadIdx.x;
    int v = (tid < nb) ? btot[tid] : 0;
    int lane = tid & 63, w = tid >> 6;
    int sc = v;
    #pragma unroll
    for (int off = 1; off < 64; off <<= 1) {
        int t = __shfl_up(sc, off);
        if (lane >= off) sc += t;
    }
    if (lane == 63) ws4[w] = sc;
    __syncthreads();
    int woff = 0;
    #pragma unroll
    for (int k = 0; k < 4; ++k)
        if (k < w) woff += ws4[k];
    if (tid < nb) btot[tid] = sc + woff - v;
}

__global__ void scan_fix_kernel(const int* __restrict__ bscan, const int* __restrict__ btot,
                                const int* __restrict__ deg, int* __restrict__ rowptr,
                                int* __restrict__ cursor, int n) {
    int i = blockIdx.x * blockDim.x + threadIdx.x;
    if (i >= n) return;
    int inc = bscan[i] + btot[i >> 8];
    rowptr[i + 1] = inc;
    cursor[i] = inc - deg[i];
    if (i == 0) rowptr[0] = 0;
}

// dst-partitioned counting-sort scatter.
__global__ __launch_bounds__(256) void scatter_kernel(const int* __restrict__ src,
                                                      const int* __restrict__ dst,
                                                      int* __restrict__ cursor,
                                                      int* __restrict__ csr_src, int E) {
    int part = blockIdx.x & 7;
    int nch = gridDim.x >> 3;
    int chunk = blockIdx.x >> 3;
    int per = (E + nch - 1) / nch;
    int beg = chunk * per;
    int end = min(E, beg + per);
    int plo = part * PARTSZ, phi = plo + PARTSZ;
    for (int e = beg + threadIdx.x; e < end; e += 256) {
        int d = dst[e];
        int s = src[e];
        if (d >= plo && d < phi) {
            int p = atomicAdd(&cursor[d], 1);
            csr_src[p] = s;
        }
    }
}

// One wave per node. Half-wave edge pairing; lane (l&31)=hl owns channels [4hl..4hl+3].
// All T-state kept as packed pre-scaled bf16 rows (bf16(T*dinv)); f32 only row-locally.
// MODE 1: gather featb -> T1 = -di*acc;           write T1b = bf16(T1*di)
// MODE 2: gather T1b   -> T2 = -2di*acc - feat;   write T2b = bf16(T2*di)
// MODE 3: gather T2b   -> t1 = T1b*rd, t2 = T2b*rd, T3 = -2di*acc - t1;
//         h = th0*f + .5*(th1 t1 + th2 t2 + th3 T3) + .5*(th1+th2+th3); write hb = bf16(h)
template <int MODE>
__global__ __launch_bounds__(256) void agg_kernel(
    const int* __restrict__ rowptr, const int* __restrict__ csr_src,
    const float* __restrict__ dinv, const float* __restrict__ rdinv,
    const unsigned* __restrict__ Xb, const float* __restrict__ feat,
    const unsigned* __restrict__ T1b, const float* __restrict__ theta,
    unsigned* __restrict__ outb, int n) {
    int wid = (blockIdx.x * blockDim.x + threadIdx.x) >> 6;
    int lane = threadIdx.x & 63;
    if (wid >= n) return;
    int half = lane >> 5;
    int hl = lane & 31;
    int beg = rowptr[wid];
    int end = rowptr[wid + 1];
    const uint2* X2 = (const uint2*)Xb;
    float a0 = 0.f, a1 = 0.f, a2 = 0.f, a3 = 0.f;
    for (int e0 = beg; e0 < end; e0 += 64) {
        int s = (e0 + lane < end) ? csr_src[e0 + lane] : 0;
        int cnt = min(64, end - e0);
        int j = 0;
        for (; j + 8 <= cnt; j += 8) {
            int s0 = __shfl(s, j + 0 + half);
            int s1 = __shfl(s, j + 2 + half);
            int s2 = __shfl(s, j + 4 + half);
            int s3 = __shfl(s, j + 6 + half);
            uint2 u0 = X2[(size_t)s0 * 32 + hl];
            uint2 u1 = X2[(size_t)s1 * 32 + hl];
            uint2 u2 = X2[(size_t)s2 * 32 + hl];
            uint2 u3 = X2[(size_t)s3 * 32 + hl];
            a0 += bf_lo(u0.x); a1 += bf_hi(u0.x); a2 += bf_lo(u0.y); a3 += bf_hi(u0.y);
            a0 += bf_lo(u1.x); a1 += bf_hi(u1.x); a2 += bf_lo(u1.y); a3 += bf_hi(u1.y);
            a0 += bf_lo(u2.x); a1 += bf_hi(u2.x); a2 += bf_lo(u2.y); a3 += bf_hi(u2.y);
            a0 += bf_lo(u3.x); a1 += bf_hi(u3.x); a2 += bf_lo(u3.y); a3 += bf_hi(u3.y);
        }
        for (; j + 2 <= cnt; j += 2) {
            int sj = __shfl(s, j + half);
            uint2 u = X2[(size_t)sj * 32 + hl];
            a0 += bf_lo(u.x); a1 += bf_hi(u.x); a2 += bf_lo(u.y); a3 += bf_hi(u.y);
        }
        if (j < cnt) {
            int sj = __shfl(s, j);
            if (half == 0) {
                uint2 u = X2[(size_t)sj * 32 + hl];
                a0 += bf_lo(u.x); a1 += bf_hi(u.x); a2 += bf_lo(u.y); a3 += bf_hi(u.y);
            }
        }
    }
    a0 += __shfl_xor(a0, 32);
    a1 += __shfl_xor(a1, 32);
    a2 += __shfl_xor(a2, 32);
    a3 += __shfl_xor(a3, 32);

    float di = dinv[wid];
    size_t row4 = (size_t)wid * 32 + hl;
    if (MODE == 1) {
        if (half == 0) {
            float r0 = -di * a0, r1 = -di * a1, r2 = -di * a2, r3 = -di * a3;
            uint2 p;
            p.x = pack_bf16(r0 * di, r1 * di);
            p.y = pack_bf16(r2 * di, r3 * di);
            ((uint2*)outb)[row4] = p;
        }
    } else if (MODE == 2) {
        if (half == 0) {
            float4 f = ((const float4*)feat)[row4];
            float r0 = -2.f * di * a0 - f.x;
            float r1 = -2.f * di * a1 - f.y;
            float r2 = -2.f * di * a2 - f.z;
            float r3 = -2.f * di * a3 - f.w;
            uint2 p;
            p.x = pack_bf16(r0 * di, r1 * di);
            p.y = pack_bf16(r2 * di, r3 * di);
            ((uint2*)outb)[row4] = p;
        }
    } else {
        if (half == 0) {
            float rd = rdinv[wid];
            float4 f = ((const float4*)feat)[row4];
            uint2 ub1 = ((const uint2*)T1b)[row4];
            uint2 ub2 = ((const uint2*)Xb)[row4];  // Xb == T2b in mode 3
            float t10 = bf_lo(ub1.x) * rd, t11 = bf_hi(ub1.x) * rd;
            float t12 = bf_lo(ub1.y) * rd, t13 = bf_hi(ub1.y) * rd;
            float t20 = bf_lo(ub2.x) * rd, t21 = bf_hi(ub2.x) * rd;
            float t22 = bf_lo(ub2.y) * rd, t23 = bf_hi(ub2.y) * rd;
            float th0 = theta[0], th1 = theta[1], th2 = theta[2], th3 = theta[3];
            float c = 0.5f * (th1 + th2 + th3);
            float t30 = -2.f * di * a0 - t10;
            float t31 = -2.f * di * a1 - t11;
            float t32 = -2.f * di * a2 - t12;
            float t33 = -2.f * di * a3 - t13;
            float r0 = th0 * f.x + 0.5f * (th1 * t10 + th2 * t20 + th3 * t30) + c;
            float r1 = th0 * f.y + 0.5f * (th1 * t11 + th2 * t21 + th3 * t31) + c;
            float r2 = th0 * f.z + 0.5f * (th1 * t12 + th2 * t22 + th3 * t32) + c;
            float r3 = th0 * f.w + 0.5f * (th1 * t13 + th2 * t23 + th3 * t33) + c;
            uint2 p;
            p.x = pack_bf16(r0, r1);
            p.y = pack_bf16(r2, r3);
            ((uint2*)outb)[row4] = p;
        }
    }
}

// BK-tiled GEMM, bf16 h input: block computes 64 nodes x 64 outs, K in 4 steps of 32.
#define BK 32
#define TS 68
__global__ __launch_bounds__(256) void gemm_kernel(const unsigned* __restrict__ hb,
                                                   const float* __restrict__ W,
                                                   float* __restrict__ out, int n) {
    __shared__ float hs[BK * TS];
    __shared__ float ws[BK * TS];
    int tid = threadIdx.x;
    int tile = blockIdx.x >> 1;
    int o0 = (blockIdx.x & 1) * 64;
    int node0 = tile * 64;
    int tx = tid & 15, ty = tid >> 4;
    const uint2* H2 = (const uint2*)hb;

    float acc[4][4] = {};

    for (int k0 = 0; k0 < D; k0 += BK) {
        __syncthreads();
        #pragma unroll
        for (int p = 0; p < 2; ++p) {
            int idx = p * 256 + tid;
            int r = idx >> 3, c = idx & 7;  // row r, 8 chunks of 4 channels
            int nn = node0 + r;
            uint2 u = make_uint2(0u, 0u);
            if (nn < n) u = H2[(size_t)nn * 32 + (k0 >> 2) + c];
            hs[(c * 4 + 0) * TS + r] = bf_lo(u.x);
            hs[(c * 4 + 1) * TS + r] = bf_hi(u.x);
            hs[(c * 4 + 2) * TS + r] = bf_lo(u.y);
            hs[(c * 4 + 3) * TS + r] = bf_hi(u.y);
            float4 wv = ((const float4*)(W + (size_t)(o0 + r) * D + k0))[c];
            ws[(c * 4 + 0) * TS + r] = wv.x;
            ws[(c * 4 + 1) * TS + r] = wv.y;
            ws[(c * 4 + 2) * TS + r] = wv.z;
            ws[(c * 4 + 3) * TS + r] = wv.w;
        }
        __syncthreads();
        #pragma unroll
        for (int kk = 0; kk < BK; ++kk) {
            float4 hv = *(const float4*)&hs[kk * TS + 4 * ty];
            float4 wv = *(const float4*)&ws[kk * TS + 4 * tx];
            float hvv[4] = {hv.x, hv.y, hv.z, hv.w};
            float wvv[4] = {wv.x, wv.y, wv.z, wv.w};
            #pragma unroll
            for (int k = 0; k < 4; ++k)
                #pragma unroll
                for (int kk2 = 0; kk2 < 4; ++kk2)
                    acc[k][kk2] = fmaf(hvv[k], wvv[kk2], acc[k][kk2]);
        }
    }

    #pragma unroll
    for (int k = 0; k < 4; ++k) {
        int nn = node0 + 4 * ty + k;
        if (nn < n) {
            float4 r4;
            r4.x = acc[k][0] > 0.f ? acc[k][0] : 0.01f * acc[k][0];
            r4.y = acc[k][1] > 0.f ? acc[k][1] : 0.01f * acc[k][1];
            r4.z = acc[k][2] > 0.f ? acc[k][2] : 0.01f * acc[k][2];
            r4.w = acc[k][3] > 0.f ? acc[k][3] : 0.01f * acc[k][3];
            ((float4*)(out + (size_t)nn * D + o0))[tx] = r4;
        }
    }
}

extern "C" void kernel_launch(void* const* d_in, const int* in_sizes, int n_in,
                              void* d_out, int out_size, void* d_ws, size_t ws_size,
                              hipStream_t stream) {
    const float* feat = (const float*)d_in[0];
    const int* src = (const int*)d_in[1];
    const int* dst = (const int*)d_in[2];
    const float* theta = (const float*)d_in[3];
    const float* W = (const float*)d_in[4];
    float* out = (float*)d_out;

    const int n = NN;
    const int E = EE;
    const int nb = (n + 255) / 256;

    char* w = (char*)d_ws;
    size_t off = 0;
    int* deg = (int*)(w + off); off = align_up(off + (size_t)n * 4, 512);
    float* dinv = (float*)(w + off); off = align_up(off + (size_t)n * 4, 512);
    float* rdinv = (float*)(w + off); off = align_up(off + (size_t)n * 4, 512);
    int* rowptr = (int*)(w + off); off = align_up(off + (size_t)(n + 1) * 4, 512);
    int* cursor = (int*)(w + off); off = align_up(off + (size_t)n * 4, 512);
    int* bscan = (int*)(w + off); off = align_up(off + (size_t)(nb * 256) * 4, 512);
    int* btot = (int*)(w + off); off = align_up(off + (size_t)256 * 4, 512);
    int* csr_src = (int*)(w + off); off = align_up(off + (size_t)E * 4, 512);
    unsigned* featb = (unsigned*)(w + off); off = align_up(off + (size_t)n * 64 * 4, 512);
    unsigned* T1b = (unsigned*)(w + off); off = align_up(off + (size_t)n * 64 * 4, 512);
    unsigned* T2b = (unsigned*)(w + off); off = align_up(off + (size_t)n * 64 * 4, 512);
    unsigned* hb = (unsigned*)(w + off); off = align_up(off + (size_t)n * 64 * 4, 512);
    (void)ws_size;

    zero_kernel<<<(n + 255) / 256, 256, 0, stream>>>(deg, n);
    deg_kernel<<<2048, 256, 0, stream>>>(dst, deg, E);
    dinv_kernel<<<(n + 255) / 256, 256, 0, stream>>>(deg, dinv, rdinv, n);
    scale_kernel<<<(n * 64 + 255) / 256, 256, 0, stream>>>(feat, dinv, featb, n);
    scan_blk_kernel<<<nb, 256, 0, stream>>>(deg, bscan, btot, n);
    scan_top_kernel<<<1, 256, 0, stream>>>(btot, nb);
    scan_fix_kernel<<<(n + 255) / 256, 256, 0, stream>>>(bscan, btot, deg, rowptr, cursor, n);
    scatter_kernel<<<2048, 256, 0, stream>>>(src, dst, cursor, csr_src, E);

    int agg_grid = (n + 3) / 4;
    agg_kernel<1><<<agg_grid, 256, 0, stream>>>(rowptr, csr_src, dinv, rdinv, featb, feat, T1b, theta, T1b, n);
    agg_kernel<2><<<agg_grid, 256, 0, stream>>>(rowptr, csr_src, dinv, rdinv, T1b, feat, T1b, theta, T2b, n);
    agg_kernel<3><<<agg_grid, 256, 0, stream>>>(rowptr, csr_src, dinv, rdinv, T2b, feat, T1b, theta, hb, n);

    int gemm_grid = ((n + 63) / 64) * 2;
    gemm_kernel<<<gemm_grid, 256, 0, stream>>>(hb, W, out, n);
}

// Round 9
// 220.011 us; speedup vs baseline: 3.5897x; 1.0348x over previous
//
#include <hip/hip_runtime.h>

#define NN 50000
#define EE 800000
#define D 128
#define PARTSZ 6250  // NN/8

static inline size_t align_up(size_t x, size_t a) { return (x + a - 1) & ~(a - 1); }

__device__ __forceinline__ unsigned pack_bf16(float a, float b) {
    unsigned ua = __float_as_uint(a), ub = __float_as_uint(b);
    unsigned ra = (ua + 0x7fffu + ((ua >> 16) & 1u)) >> 16;
    unsigned rb = (ub + 0x7fffu + ((ub >> 16) & 1u)) & 0xffff0000u;
    return ra | rb;
}
__device__ __forceinline__ float bf_lo(unsigned u) { return __uint_as_float(u << 16); }
__device__ __forceinline__ float bf_hi(unsigned u) { return __uint_as_float(u & 0xffff0000u); }

__global__ void zero_kernel(int* __restrict__ p, int n) {
    int i = blockIdx.x * blockDim.x + threadIdx.x;
    if (i < n) p[i] = 0;
}

// dst-partitioned degree histogram: block b covers chunk b>>3, partition b&7.
__global__ __launch_bounds__(256) void deg_kernel(const int* __restrict__ dst,
                                                  int* __restrict__ deg, int E) {
    int part = blockIdx.x & 7;
    int nch = gridDim.x >> 3;
    int chunk = blockIdx.x >> 3;
    int per = (E + nch - 1) / nch;
    int beg = chunk * per;
    int end = min(E, beg + per);
    int plo = part * PARTSZ, phi = plo + PARTSZ;
    for (int e = beg + threadIdx.x; e < end; e += 256) {
        int d = dst[e];
        if (d >= plo && d < phi) atomicAdd(&deg[d], 1);
    }
}

__global__ void dinv_kernel(const int* __restrict__ deg, float* __restrict__ dinv,
                            float* __restrict__ rdinv, int n) {
    int i = blockIdx.x * blockDim.x + threadIdx.x;
    if (i < n) {
        float d = (float)deg[i];
        if (d < 1.0f) d = 1.0f;
        dinv[i] = rsqrtf(d);
        rdinv[i] = sqrtf(d);
    }
}

__global__ void scale_kernel(const float* __restrict__ feat, const float* __restrict__ dinv,
                             unsigned* __restrict__ featb, int n) {
    int idx = blockIdx.x * blockDim.x + threadIdx.x;
    if (idx >= n * 64) return;
    int i = idx >> 6;
    float di = dinv[i];
    float2 f = ((const float2*)feat)[idx];
    featb[idx] = pack_bf16(f.x * di, f.y * di);
}

__global__ void scan_blk_kernel(const int* __restrict__ deg, int* __restrict__ bscan,
                                int* __restrict__ btot, int n) {
    __shared__ int ws4[4];
    int tid = threadIdx.x, b = blockIdx.x;
    int i = b * 256 + tid;
    int v = (i < n) ? deg[i] : 0;
    int lane = tid & 63, w = tid >> 6;
    int sc = v;
    #pragma unroll
    for (int off = 1; off < 64; off <<= 1) {
        int t = __shfl_up(sc, off);
        if (lane >= off) sc += t;
    }
    if (lane == 63) ws4[w] = sc;
    __syncthreads();
    int woff = 0;
    #pragma unroll
    for (int k = 0; k < 4; ++k)
        if (k < w) woff += ws4[k];
    int inc = sc + woff;
    bscan[b * 256 + tid] = inc;
    if (tid == 255) btot[b] = inc;
}

__global__ void scan_top_kernel(int* __restrict__ btot, int nb) {
    __shared__ int ws4[4];
    int tid = threadIdx.x;
    int v = (tid < nb) ? btot[tid] : 0;
    int lane = tid & 63, w = tid >> 6;
    int sc = v;
    #pragma unroll
    for (int off = 1; off < 64; off <<= 1) {
        int t = __shfl_up(sc, off);
        if (lane >= off) sc += t;
    }
    if (lane == 63) ws4[w] = sc;
    __syncthreads();
    int woff = 0;
    #pragma unroll
    for (int k = 0; k < 4; ++k)
        if (k < w) woff += ws4[k];
    if (tid < nb) btot[tid] = sc + woff - v;
}

__global__ void scan_fix_kernel(const int* __restrict__ bscan, const int* __restrict__ btot,
                                const int* __restrict__ deg, int* __restrict__ rowptr,
                                int* __restrict__ cursor, int n) {
    int i = blockIdx.x * blockDim.x + threadIdx.x;
    if (i >= n) return;
    int inc = bscan[i] + btot[i >> 8];
    rowptr[i + 1] = inc;
    cursor[i] = inc - deg[i];
    if (i == 0) rowptr[0] = 0;
}

// dst-partitioned counting-sort scatter.
__global__ __launch_bounds__(256) void scatter_kernel(const int* __restrict__ src,
                                                      const int* __restrict__ dst,
                                                      int* __restrict__ cursor,
                                                      int* __restrict__ csr_src, int E) {
    int part = blockIdx.x & 7;
    int nch = gridDim.x >> 3;
    int chunk = blockIdx.x >> 3;
    int per = (E + nch - 1) / nch;
    int beg = chunk * per;
    int end = min(E, beg + per);
    int plo = part * PARTSZ, phi = plo + PARTSZ;
    for (int e = beg + threadIdx.x; e < end; e += 256) {
        int d = dst[e];
        if (d >= plo && d < phi) {
            int s = src[e];
            int p = atomicAdd(&cursor[d], 1);
            csr_src[p] = s;
        }
    }
}

#define ACC8(u) do { \
    a0 += bf_lo((u).x); a1 += bf_hi((u).x); \
    a2 += bf_lo((u).y); a3 += bf_hi((u).y); \
    a4 += bf_lo((u).z); a5 += bf_hi((u).z); \
    a6 += bf_lo((u).w); a7 += bf_hi((u).w); } while (0)

// One wave per node. Quarter-wave edge mapping: quarter q = lane>>4 handles edge
// j+4k+q; lane hq = lane&15 owns channels [8hq..8hq+7] via a uint4 (16B) load.
// All T-state is packed pre-scaled bf16 (bf16(T*dinv)); f32 only row-locally.
// MODE 1: T1b = -di^2 * acc
// MODE 2: T2b = -2 di^2 acc - featb
// MODE 3: t1=T1b*rd, t2=T2b*rd, f=featb*rd, T3=-2di*acc - t1;
//         hb = bf16(th0 f + .5(th1 t1 + th2 t2 + th3 T3) + .5(th1+th2+th3))
template <int MODE>
__global__ __launch_bounds__(256) void agg_kernel(
    const int* __restrict__ rowptr, const int* __restrict__ csr_src,
    const float* __restrict__ dinv, const float* __restrict__ rdinv,
    const unsigned* __restrict__ Xb, const unsigned* __restrict__ featb,
    const unsigned* __restrict__ T1b, const float* __restrict__ theta,
    unsigned* __restrict__ outb, int n) {
    int wid = (blockIdx.x * blockDim.x + threadIdx.x) >> 6;
    int lane = threadIdx.x & 63;
    if (wid >= n) return;
    int q = lane >> 4;
    int hq = lane & 15;
    int beg = rowptr[wid];
    int end = rowptr[wid + 1];
    const uint4* X4 = (const uint4*)Xb;
    float a0 = 0.f, a1 = 0.f, a2 = 0.f, a3 = 0.f, a4 = 0.f, a5 = 0.f, a6 = 0.f, a7 = 0.f;
    for (int e0 = beg; e0 < end; e0 += 64) {
        int s = (e0 + lane < end) ? csr_src[e0 + lane] : 0;
        int cnt = min(64, end - e0);
        int j = 0;
        for (; j + 16 <= cnt; j += 16) {
            int s0 = __shfl(s, j + q);
            int s1 = __shfl(s, j + 4 + q);
            int s2 = __shfl(s, j + 8 + q);
            int s3 = __shfl(s, j + 12 + q);
            uint4 u0 = X4[(size_t)s0 * 16 + hq];
            uint4 u1 = X4[(size_t)s1 * 16 + hq];
            uint4 u2 = X4[(size_t)s2 * 16 + hq];
            uint4 u3 = X4[(size_t)s3 * 16 + hq];
            ACC8(u0); ACC8(u1); ACC8(u2); ACC8(u3);
        }
        for (; j + 4 <= cnt; j += 4) {
            int s0 = __shfl(s, j + q);
            uint4 u0 = X4[(size_t)s0 * 16 + hq];
            ACC8(u0);
        }
        int rem = cnt - j;
        if (rem > 0) {
            int idx = j + q;
            if (idx >= cnt) idx = cnt - 1;
            int sj = __shfl(s, idx);
            if (q < rem) {
                uint4 u = X4[(size_t)sj * 16 + hq];
                ACC8(u);
            }
        }
    }
    // fold the four quarters
    a0 += __shfl_xor(a0, 16); a0 += __shfl_xor(a0, 32);
    a1 += __shfl_xor(a1, 16); a1 += __shfl_xor(a1, 32);
    a2 += __shfl_xor(a2, 16); a2 += __shfl_xor(a2, 32);
    a3 += __shfl_xor(a3, 16); a3 += __shfl_xor(a3, 32);
    a4 += __shfl_xor(a4, 16); a4 += __shfl_xor(a4, 32);
    a5 += __shfl_xor(a5, 16); a5 += __shfl_xor(a5, 32);
    a6 += __shfl_xor(a6, 16); a6 += __shfl_xor(a6, 32);
    a7 += __shfl_xor(a7, 16); a7 += __shfl_xor(a7, 32);

    if (q != 0) return;
    float di = dinv[wid];
    size_t r16 = (size_t)wid * 16 + hq;
    uint4 p;
    if (MODE == 1) {
        float m = -di * di;
        p.x = pack_bf16(m * a0, m * a1);
        p.y = pack_bf16(m * a2, m * a3);
        p.z = pack_bf16(m * a4, m * a5);
        p.w = pack_bf16(m * a6, m * a7);
    } else if (MODE == 2) {
        uint4 fb = ((const uint4*)featb)[r16];
        float m = -2.f * di * di;
        p.x = pack_bf16(m * a0 - bf_lo(fb.x), m * a1 - bf_hi(fb.x));
        p.y = pack_bf16(m * a2 - bf_lo(fb.y), m * a3 - bf_hi(fb.y));
        p.z = pack_bf16(m * a4 - bf_lo(fb.z), m * a5 - bf_hi(fb.z));
        p.w = pack_bf16(m * a6 - bf_lo(fb.w), m * a7 - bf_hi(fb.w));
    } else {
        uint4 fb = ((const uint4*)featb)[r16];
        uint4 b1 = ((const uint4*)T1b)[r16];
        uint4 b2 = ((const uint4*)Xb)[r16];  // Xb == T2b in mode 3
        float rd = rdinv[wid];
        float th0 = theta[0], th1 = theta[1], th2 = theta[2], th3 = theta[3];
        float c = 0.5f * (th1 + th2 + th3);
        float h[8];
        float av[8] = {a0, a1, a2, a3, a4, a5, a6, a7};
        float fv[8] = {bf_lo(fb.x), bf_hi(fb.x), bf_lo(fb.y), bf_hi(fb.y),
                       bf_lo(fb.z), bf_hi(fb.z), bf_lo(fb.w), bf_hi(fb.w)};
        float t1v[8] = {bf_lo(b1.x), bf_hi(b1.x), bf_lo(b1.y), bf_hi(b1.y),
                        bf_lo(b1.z), bf_hi(b1.z), bf_lo(b1.w), bf_hi(b1.w)};
        float t2v[8] = {bf_lo(b2.x), bf_hi(b2.x), bf_lo(b2.y), bf_hi(b2.y),
                        bf_lo(b2.z), bf_hi(b2.z), bf_lo(b2.w), bf_hi(b2.w)};
        #pragma unroll
        for (int k = 0; k < 8; ++k) {
            float t1 = t1v[k] * rd;
            float t2 = t2v[k] * rd;
            float f = fv[k] * rd;
            float t3 = -2.f * di * av[k] - t1;
            h[k] = th0 * f + 0.5f * (th1 * t1 + th2 * t2 + th3 * t3) + c;
        }
        p.x = pack_bf16(h[0], h[1]);
        p.y = pack_bf16(h[2], h[3]);
        p.z = pack_bf16(h[4], h[5]);
        p.w = pack_bf16(h[6], h[7]);
    }
    ((uint4*)outb)[r16] = p;
}

// BK-tiled GEMM, bf16 h input: block computes 64 nodes x 64 outs, K in 4 steps of 32.
#define BK 32
#define TS 68
__global__ __launch_bounds__(256) void gemm_kernel(const unsigned* __restrict__ hb,
                                                   const float* __restrict__ W,
                                                   float* __restrict__ out, int n) {
    __shared__ float hs[BK * TS];
    __shared__ float ws[BK * TS];
    int tid = threadIdx.x;
    int tile = blockIdx.x >> 1;
    int o0 = (blockIdx.x & 1) * 64;
    int node0 = tile * 64;
    int tx = tid & 15, ty = tid >> 4;
    const uint2* H2 = (const uint2*)hb;

    float acc[4][4] = {};

    for (int k0 = 0; k0 < D; k0 += BK) {
        __syncthreads();
        #pragma unroll
        for (int p = 0; p < 2; ++p) {
            int idx = p * 256 + tid;
            int r = idx >> 3, c = idx & 7;
            int nn = node0 + r;
            uint2 u = make_uint2(0u, 0u);
            if (nn < n) u = H2[(size_t)nn * 32 + (k0 >> 2) + c];
            hs[(c * 4 + 0) * TS + r] = bf_lo(u.x);
            hs[(c * 4 + 1) * TS + r] = bf_hi(u.x);
            hs[(c * 4 + 2) * TS + r] = bf_lo(u.y);
            hs[(c * 4 + 3) * TS + r] = bf_hi(u.y);
            float4 wv = ((const float4*)(W + (size_t)(o0 + r) * D + k0))[c];
            ws[(c * 4 + 0) * TS + r] = wv.x;
            ws[(c * 4 + 1) * TS + r] = wv.y;
            ws[(c * 4 + 2) * TS + r] = wv.z;
            ws[(c * 4 + 3) * TS + r] = wv.w;
        }
        __syncthreads();
        #pragma unroll
        for (int kk = 0; kk < BK; ++kk) {
            float4 hv = *(const float4*)&hs[kk * TS + 4 * ty];
            float4 wv = *(const float4*)&ws[kk * TS + 4 * tx];
            float hvv[4] = {hv.x, hv.y, hv.z, hv.w};
            float wvv[4] = {wv.x, wv.y, wv.z, wv.w};
            #pragma unroll
            for (int k = 0; k < 4; ++k)
                #pragma unroll
                for (int kk2 = 0; kk2 < 4; ++kk2)
                    acc[k][kk2] = fmaf(hvv[k], wvv[kk2], acc[k][kk2]);
        }
    }

    #pragma unroll
    for (int k = 0; k < 4; ++k) {
        int nn = node0 + 4 * ty + k;
        if (nn < n) {
            float4 r4;
            r4.x = acc[k][0] > 0.f ? acc[k][0] : 0.01f * acc[k][0];
            r4.y = acc[k][1] > 0.f ? acc[k][1] : 0.01f * acc[k][1];
            r4.z = acc[k][2] > 0.f ? acc[k][2] : 0.01f * acc[k][2];
            r4.w = acc[k][3] > 0.f ? acc[k][3] : 0.01f * acc[k][3];
            ((float4*)(out + (size_t)nn * D + o0))[tx] = r4;
        }
    }
}

extern "C" void kernel_launch(void* const* d_in, const int* in_sizes, int n_in,
                              void* d_out, int out_size, void* d_ws, size_t ws_size,
                              hipStream_t stream) {
    const float* feat = (const float*)d_in[0];
    const int* src = (const int*)d_in[1];
    const int* dst = (const int*)d_in[2];
    const float* theta = (const float*)d_in[3];
    const float* W = (const float*)d_in[4];
    float* out = (float*)d_out;

    const int n = NN;
    const int E = EE;
    const int nb = (n + 255) / 256;

    char* w = (char*)d_ws;
    size_t off = 0;
    int* deg = (int*)(w + off); off = align_up(off + (size_t)n * 4, 512);
    float* dinv = (float*)(w + off); off = align_up(off + (size_t)n * 4, 512);
    float* rdinv = (float*)(w + off); off = align_up(off + (size_t)n * 4, 512);
    int* rowptr = (int*)(w + off); off = align_up(off + (size_t)(n + 1) * 4, 512);
    int* cursor = (int*)(w + off); off = align_up(off + (size_t)n * 4, 512);
    int* bscan = (int*)(w + off); off = align_up(off + (size_t)(nb * 256) * 4, 512);
    int* btot = (int*)(w + off); off = align_up(off + (size_t)256 * 4, 512);
    int* csr_src = (int*)(w + off); off = align_up(off + (size_t)E * 4, 512);
    unsigned* featb = (unsigned*)(w + off); off = align_up(off + (size_t)n * 64 * 4, 512);
    unsigned* T1b = (unsigned*)(w + off); off = align_up(off + (size_t)n * 64 * 4, 512);
    unsigned* T2b = (unsigned*)(w + off); off = align_up(off + (size_t)n * 64 * 4, 512);
    unsigned* hb = (unsigned*)(w + off); off = align_up(off + (size_t)n * 64 * 4, 512);
    (void)ws_size;

    zero_kernel<<<(n + 255) / 256, 256, 0, stream>>>(deg, n);
    deg_kernel<<<2048, 256, 0, stream>>>(dst, deg, E);
    dinv_kernel<<<(n + 255) / 256, 256, 0, stream>>>(deg, dinv, rdinv, n);
    scale_kernel<<<(n * 64 + 255) / 256, 256, 0, stream>>>(feat, dinv, featb, n);
    scan_blk_kernel<<<nb, 256, 0, stream>>>(deg, bscan, btot, n);
    scan_top_kernel<<<1, 256, 0, stream>>>(btot, nb);
    scan_fix_kernel<<<(n + 255) / 256, 256, 0, stream>>>(bscan, btot, deg, rowptr, cursor, n);
    scatter_kernel<<<2048, 256, 0, stream>>>(src, dst, cursor, csr_src, E);

    int agg_grid = (n + 3) / 4;
    agg_kernel<1><<<agg_grid, 256, 0, stream>>>(rowptr, csr_src, dinv, rdinv, featb, featb, T1b, theta, T1b, n);
    agg_kernel<2><<<agg_grid, 256, 0, stream>>>(rowptr, csr_src, dinv, rdinv, T1b, featb, T1b, theta, T2b, n);
    agg_kernel<3><<<agg_grid, 256, 0, stream>>>(rowptr, csr_src, dinv, rdinv, T2b, featb, T1b, theta, hb, n);

    int gemm_grid = ((n + 63) / 64) * 2;
    gemm_kernel<<<gemm_grid, 256, 0, stream>>>(hb, W, out, n);
}